// Round 4
// baseline (383.352 us; speedup 1.0000x reference)
//
#include <hip/hip_runtime.h>
#include <cstdint>
#include <cmath>

// ---------------- tunables ----------------
#define SLICES 16
#define SUBCAP 640
#define CAPT (SLICES * SUBCAP)   // 10240
#define NB4 4096                 // k4 histogram bins
#define NCH 512                  // NB4/8 chunk sums
#define KTHR 1024                // k4 block size
#define K1T 256                  // k1 block size
#define THRC 1.7f                // k1 collect threshold = mu + THRC*sigma

// order-preserving float<->uint bijection
static __device__ __forceinline__ uint32_t f2u(float f) {
    uint32_t b = __float_as_uint(f);
    return (b & 0x80000000u) ? ~b : (b | 0x80000000u);
}
static __device__ __forceinline__ float u2f(uint32_t u) {
    uint32_t b = (u & 0x80000000u) ? (u ^ 0x80000000u) : ~u;
    return __uint_as_float(b);
}

static __device__ __forceinline__ uint32_t wave_incl_u(uint32_t v) {
    int lane = threadIdx.x & 63;
#pragma unroll
    for (int o = 1; o < 64; o <<= 1) {
        uint32_t t = __shfl_up(v, (unsigned)o);
        if (lane >= o) v += t;
    }
    return v;
}
static __device__ __forceinline__ float wave_incl_f(float v) {
    int lane = threadIdx.x & 63;
#pragma unroll
    for (int o = 1; o < 64; o <<= 1) {
        float t = __shfl_up(v, (unsigned)o);
        if (lane >= o) v += t;
    }
    return v;
}

// ---------------- legacy wave descents (used by fallback kernel) ----------------

static __device__ void wave_desc_count(const uint32_t* h, int hi, int lo, uint32_t target,
                                       int* out_bin, uint32_t* out_above) {
    if (threadIdx.x < 64) {
        int lane = threadIdx.x;
        uint32_t S = 0;
        for (int r0 = hi; r0 >= lo; r0 -= 64) {
            int b = r0 - lane;
            uint32_t w = (b >= lo) ? h[b] : 0u;
            uint32_t incl = wave_incl_u(w);
            uint32_t Sb = S + incl - w;
            bool cross = (Sb < target) && (Sb + w >= target);
            unsigned long long m = __ballot(cross);
            if (m) {
                int l = (int)__ffsll(m) - 1;
                if (lane == l) { *out_bin = b; *out_above = Sb; }
                return;
            }
            S += __shfl(incl, 63);
        }
        if (lane == 0) { *out_bin = -1; *out_above = S; }
    }
}
static __device__ void wave_desc_wcross(const float* h, int hi, int lo, float base, float target,
                                        int* out_bin, float* out_S) {
    if (threadIdx.x < 64) {
        int lane = threadIdx.x;
        float S = base;
        for (int r0 = hi; r0 >= lo; r0 -= 64) {
            int b = r0 - lane;
            float w = (b >= lo) ? h[b] : 0.f;
            float incl = wave_incl_f(w);
            float Sb = S + (incl - w);
            bool cross = (Sb < target) && (Sb + w >= target);
            unsigned long long m = __ballot(cross);
            if (m) {
                int l = (int)__ffsll(m) - 1;
                if (lane == l) { *out_bin = b; *out_S = Sb; }
                return;
            }
            S += __shfl(incl, 63);
        }
        if (lane == 0) { *out_bin = -1; *out_S = S; }
    }
}
static __device__ void wave_desc_wvalue(const float* h, int hi, int lo, float base, float target,
                                        int* out_bin, float* out_S) {
    if (threadIdx.x < 64) {
        int lane = threadIdx.x;
        float S = base;
        for (int r0 = hi; r0 >= lo; r0 -= 64) {
            int b = r0 - lane;
            float w = (b >= lo) ? h[b] : 0.f;
            float incl = wave_incl_f(w);
            float Sb = S + (incl - w);
            bool cross = (w > 0.f) && (Sb >= target);
            unsigned long long m = __ballot(cross);
            if (m) {
                int l = (int)__ffsll(m) - 1;
                if (lane == l) { *out_bin = b; *out_S = Sb; }
                return;
            }
            S += __shfl(incl, 63);
        }
        if (lane == 0) { *out_bin = -1; *out_S = S; }
    }
}

// ---------------- K1: stats-threshold collect (no histogram, no atomics) ----------------

__global__ __launch_bounds__(K1T) void k1_collect(
    const float* __restrict__ logits, const float* __restrict__ temps,
    uint32_t* __restrict__ cand_u, int* __restrict__ cand_ix,
    uint32_t* __restrict__ candCnt, int V, int sliceLen)
{
    const int row = blockIdx.y, slice = blockIdx.x, tid = threadIdx.x;
    const int lane = tid & 63, wv = tid >> 6;
    __shared__ float redm[4], reds[4], redq[4];
    __shared__ float s_thr;
    __shared__ int wsum[4];
    __shared__ int s_base;

    const int base = slice * sliceLen;
    int len = V - base;
    if (len > sliceLen) len = sliceLen;
    if (len <= 0) { if (tid == 0) candCnt[row * SLICES + slice] = 0u; return; }

    const float* lg = logits + (size_t)row * (size_t)V;
    const float4* p4 = (const float4*)(lg + base);
    const int n4 = len >> 2;

    // pass 1: raw-logit stats (max, sum, sumsq) — fully vectorized
    float mx = -INFINITY, sm = 0.f, sq = 0.f;
    for (int i = tid; i < n4; i += K1T) {
        float4 v = p4[i];
        mx = fmaxf(mx, fmaxf(fmaxf(v.x, v.y), fmaxf(v.z, v.w)));
        sm += (v.x + v.y) + (v.z + v.w);
        sq += (v.x * v.x + v.y * v.y) + (v.z * v.z + v.w * v.w);
    }
#pragma unroll
    for (int o = 32; o > 0; o >>= 1) {
        mx = fmaxf(mx, __shfl_xor(mx, o));
        sm += __shfl_xor(sm, o);
        sq += __shfl_xor(sq, o);
    }
    if (lane == 0) { redm[wv] = mx; reds[wv] = sm; redq[wv] = sq; }
    __syncthreads();
    if (tid == 0) {
        float m = redm[0], s = reds[0], q = redq[0];
        for (int w = 1; w < 4; w++) { m = fmaxf(m, redm[w]); s += reds[w]; q += redq[w]; }
        float inv = 1.f / (float)len;
        float mu = s * inv;
        float var = fmaxf(q * inv - mu * mu, 0.f);
        float thr = mu + THRC * sqrtf(var);
        if (thr > m) thr = m;   // always keep at least the slice max
        s_thr = thr;
        s_base = 0;
    }
    __syncthreads();
    const float thr = s_thr;
    const float t = temps[row];
    uint32_t* cu = cand_u + ((size_t)row * SLICES + slice) * SUBCAP;
    int* cix = cand_ix + ((size_t)row * SLICES + slice) * SUBCAP;

    // pass 2: deterministic compaction of raw a >= thr ; store u = f2u(a/t)
    for (int c0 = 0; c0 < len; c0 += K1T * 4) {
        const int i0 = c0 + tid * 4;
        bool k0 = false, k1b = false, k2b = false, k3b = false;
        float4 v = make_float4(0.f, 0.f, 0.f, 0.f);
        if (i0 < len) {   // len % 4 == 0 -> all four valid
            v = *(const float4*)(lg + base + i0);
            k0 = (v.x >= thr); k1b = (v.y >= thr); k2b = (v.z >= thr); k3b = (v.w >= thr);
        }
        int cnt = (int)k0 + (int)k1b + (int)k2b + (int)k3b;
        int inc = cnt;
#pragma unroll
        for (int o = 1; o < 64; o <<= 1) {
            int x = __shfl_up(inc, (unsigned)o);
            if (lane >= o) inc += x;
        }
        if (lane == 63) wsum[wv] = inc;
        __syncthreads();
        int woff = 0;
        for (int w = 0; w < wv; w++) woff += wsum[w];
        const int tot = wsum[0] + wsum[1] + wsum[2] + wsum[3];
        int p = s_base + woff + inc - cnt;
        if (k0)  { if (p < SUBCAP) { cu[p] = f2u(v.x / t); cix[p] = base + i0;     } p++; }
        if (k1b) { if (p < SUBCAP) { cu[p] = f2u(v.y / t); cix[p] = base + i0 + 1; } p++; }
        if (k2b) { if (p < SUBCAP) { cu[p] = f2u(v.z / t); cix[p] = base + i0 + 2; } p++; }
        if (k3b) { if (p < SUBCAP) { cu[p] = f2u(v.w / t); cix[p] = base + i0 + 3; } p++; }
        __syncthreads();
        if (tid == 0) s_base += tot;
        __syncthreads();
    }
    if (tid == 0) {
        int c = s_base; if (c > SUBCAP) c = SUBCAP;
        candCnt[row * SLICES + slice] = (uint32_t)c;
    }
}

// ---------------- K4 block reductions (16 waves) ----------------

static __device__ __forceinline__ unsigned long long shflxor_u64(unsigned long long v, int o) {
    uint32_t lo = (uint32_t)v, hi = (uint32_t)(v >> 32);
    lo = __shfl_xor(lo, o); hi = __shfl_xor(hi, o);
    return ((unsigned long long)hi << 32) | (unsigned long long)lo;
}
static __device__ float k4_sum(float v, float* rb) {
#pragma unroll
    for (int o = 32; o > 0; o >>= 1) v += __shfl_xor(v, o);
    const int wv = threadIdx.x >> 6;
    if ((threadIdx.x & 63) == 0) rb[wv] = v;
    __syncthreads();
    float r = (threadIdx.x < 16) ? rb[threadIdx.x] : 0.f;
    if (threadIdx.x < 64) {
#pragma unroll
        for (int o = 8; o > 0; o >>= 1) r += __shfl_xor(r, o);
        if (threadIdx.x == 0) rb[0] = r;
    }
    __syncthreads();
    r = rb[0];
    __syncthreads();
    return r;
}
static __device__ uint32_t k4_max_u32(uint32_t v, uint32_t* rb) {
#pragma unroll
    for (int o = 32; o > 0; o >>= 1) { uint32_t x = __shfl_xor(v, o); if (x > v) v = x; }
    const int wv = threadIdx.x >> 6;
    if ((threadIdx.x & 63) == 0) rb[wv] = v;
    __syncthreads();
    uint32_t r = (threadIdx.x < 16) ? rb[threadIdx.x] : 0u;
    if (threadIdx.x < 64) {
#pragma unroll
        for (int o = 8; o > 0; o >>= 1) { uint32_t x = __shfl_xor(r, o); if (x > r) r = x; }
        if (threadIdx.x == 0) rb[0] = r;
    }
    __syncthreads();
    r = rb[0];
    __syncthreads();
    return r;
}
static __device__ uint32_t k4_min_u32(uint32_t v, uint32_t* rb) {
#pragma unroll
    for (int o = 32; o > 0; o >>= 1) { uint32_t x = __shfl_xor(v, o); if (x < v) v = x; }
    const int wv = threadIdx.x >> 6;
    if ((threadIdx.x & 63) == 0) rb[wv] = v;
    __syncthreads();
    uint32_t r = (threadIdx.x < 16) ? rb[threadIdx.x] : 0xFFFFFFFFu;
    if (threadIdx.x < 64) {
#pragma unroll
        for (int o = 8; o > 0; o >>= 1) { uint32_t x = __shfl_xor(r, o); if (x < r) r = x; }
        if (threadIdx.x == 0) rb[0] = r;
    }
    __syncthreads();
    r = rb[0];
    __syncthreads();
    return r;
}
static __device__ unsigned long long k4_max_u64(unsigned long long v, unsigned long long* rb) {
#pragma unroll
    for (int o = 32; o > 0; o >>= 1) { unsigned long long x = shflxor_u64(v, o); if (x > v) v = x; }
    const int wv = threadIdx.x >> 6;
    if ((threadIdx.x & 63) == 0) rb[wv] = v;
    __syncthreads();
    unsigned long long r = (threadIdx.x < 16) ? rb[threadIdx.x] : 0ull;
    if (threadIdx.x < 64) {
#pragma unroll
        for (int o = 8; o > 0; o >>= 1) { unsigned long long x = shflxor_u64(r, o); if (x > r) r = x; }
        if (threadIdx.x == 0) rb[0] = r;
    }
    __syncthreads();
    r = rb[0];
    __syncthreads();
    return r;
}

// ---------------- K4 chunked block descents over 4096 bins ----------------
// counts: find bin b (desc) with above < target <= above + h[b]
static __device__ void blk_desc_count(const uint32_t* __restrict__ h, uint32_t target,
                                      uint32_t* csum, int* out_bin, uint32_t* out_above)
{
    const int tid = threadIdx.x;
    for (int c = tid; c < NCH; c += KTHR) {
        uint32_t s = 0;
#pragma unroll
        for (int j = 0; j < 8; j++) s += h[c * 8 + j];
        csum[c] = s;
    }
    __syncthreads();
    if (tid < 64) {
        const int lane = tid;
        uint32_t S = 0;
        bool done = false;
        for (int r0 = NCH - 1; r0 >= 0 && !done; r0 -= 64) {
            int c = r0 - lane;
            uint32_t w = (c >= 0) ? csum[c] : 0u;
            uint32_t incl = wave_incl_u(w);
            uint32_t Sb = S + incl - w;
            bool cross = (Sb < target) && (Sb + w >= target);
            unsigned long long m = __ballot(cross);
            if (m) {
                int l = (int)__ffsll(m) - 1;
                uint32_t Sl = __shfl(Sb, l);
                int cl = __shfl(c, l);
                if (lane == 0) {
                    uint32_t s2 = Sl; int bf = -1;
                    for (int b = cl * 8 + 7; b >= 0; b--) {
                        uint32_t wb = h[b];
                        if (s2 < target && s2 + wb >= target) { bf = b; break; }
                        s2 += wb;
                    }
                    *out_bin = bf; *out_above = s2;
                }
                done = true;
            } else {
                S += __shfl(incl, 63);
            }
        }
        if (!done && lane == 0) { *out_bin = -1; *out_above = S; }
    }
    __syncthreads();
}
// weighted crossing: Sb < target <= Sb + w[b]
static __device__ void blk_desc_wcross(const float* __restrict__ h, float Sbase, float target,
                                       float* csum, int* out_bin, float* out_S)
{
    const int tid = threadIdx.x;
    for (int c = tid; c < NCH; c += KTHR) {
        float s = 0.f;
#pragma unroll
        for (int j = 0; j < 8; j++) s += h[c * 8 + j];
        csum[c] = s;
    }
    __syncthreads();
    if (tid < 64) {
        const int lane = tid;
        float S = Sbase;
        bool done = false;
        for (int r0 = NCH - 1; r0 >= 0 && !done; r0 -= 64) {
            int c = r0 - lane;
            float w = (c >= 0) ? csum[c] : 0.f;
            float incl = wave_incl_f(w);
            float Sb = S + (incl - w);
            bool cross = (Sb < target) && (Sb + w >= target);
            unsigned long long m = __ballot(cross);
            if (m) {
                int l = (int)__ffsll(m) - 1;
                float Sl = __shfl(Sb, l);
                int cl = __shfl(c, l);
                if (lane == 0) {
                    float s2 = Sl; int bf = -1;
                    for (int b = cl * 8 + 7; b >= 0; b--) {
                        float wb = h[b];
                        if (s2 < target && s2 + wb >= target) { bf = b; break; }
                        s2 += wb;
                    }
                    *out_bin = bf; *out_S = s2;
                }
                done = true;
            } else {
                S += __shfl(incl, 63);
            }
        }
        if (!done && lane == 0) { *out_bin = -1; *out_S = S; }
    }
    __syncthreads();
}
// weighted VALUE rule: first nonempty bin with Sb >= target
static __device__ void blk_desc_wvalue(const float* __restrict__ h, float Sbase, float target,
                                       float* csum, int* out_bin, float* out_S)
{
    const int tid = threadIdx.x;
    for (int c = tid; c < NCH; c += KTHR) {
        float s = 0.f;
#pragma unroll
        for (int j = 0; j < 8; j++) s += h[c * 8 + j];
        csum[c] = s;
    }
    __syncthreads();
    if (tid < 64) {
        const int lane = tid;
        float S = Sbase;
        bool done = false;
        for (int r0 = NCH - 1; r0 >= 0 && !done; r0 -= 64) {
            int c = r0 - lane;
            float w = (c >= 0) ? csum[c] : 0.f;
            float incl = wave_incl_f(w);
            float Sb = S + (incl - w);
            bool gate = (Sb + w >= target);
            unsigned long long m = __ballot(gate);
            if (m) {
                int l = (int)__ffsll(m) - 1;
                float Sl = __shfl(Sb, l);
                int cl = __shfl(c, l);
                if (lane == 0) {
                    float s2 = Sl; int bf = -1;
                    for (int b = cl * 8 + 7; b >= 0; b--) {
                        float wb = h[b];
                        if (wb > 0.f && s2 >= target) { bf = b; break; }
                        s2 += wb;
                    }
                    *out_bin = bf; *out_S = s2;
                }
                done = true;
            } else {
                S += __shfl(incl, 63);
            }
        }
        if (!done && lane == 0) { *out_bin = -1; *out_S = S; }
    }
    __syncthreads();
}

// ---------------- K4: per-row finalize ----------------

__global__ __launch_bounds__(KTHR, 1) void k4_final(
    const int* __restrict__ topks, const float* __restrict__ topps,
    const float* __restrict__ minps, const float* __restrict__ noise,
    const uint32_t* __restrict__ candCnt, const uint32_t* __restrict__ cand_u,
    const int* __restrict__ cand_ix, int* __restrict__ out, int V)
{
    const int row = blockIdx.x, tid = threadIdx.x;
    __shared__ uint32_t s_u[CAPT];
    __shared__ int s_ix[CAPT];
    __shared__ uint32_t s_cnt[NB4];
    __shared__ float s_ww[NB4];
    __shared__ float s_w0[NB4];
    __shared__ uint32_t s_csU[NCH];
    __shared__ float s_csF[NCH];
    __shared__ int s_off[SLICES + 1];
    __shared__ float rbf[16];
    __shared__ uint32_t rbu[16];
    __shared__ unsigned long long rbq[16];
    __shared__ int sh_bin; __shared__ uint32_t sh_above; __shared__ float sh_S;

    if (tid == 0) {
        int a = 0;
        for (int s = 0; s < SLICES; s++) {
            s_off[s] = a;
            int c = (int)candCnt[row * SLICES + s];
            if (c > SUBCAP) c = SUBCAP;
            a += c;
        }
        s_off[SLICES] = a;
    }
    __syncthreads();
    const int n = s_off[SLICES];
    uint32_t um = 0u, un = 0xFFFFFFFFu;
    for (int s = 0; s < SLICES; s++) {
        const int o0 = s_off[s], c = s_off[s + 1] - o0;
        const size_t gb = ((size_t)row * SLICES + s) * SUBCAP;
        for (int j = tid; j < c; j += KTHR) {
            uint32_t u = cand_u[gb + j];
            s_u[o0 + j] = u;
            s_ix[o0 + j] = cand_ix[gb + j];
            if (u > um) um = u;
            if (u < un) un = u;
        }
    }
    __syncthreads();
    const uint32_t umax = k4_max_u32(um, rbu);
    const uint32_t base = k4_min_u32(un, rbu);
    const uint32_t R = umax - base;
    int s0 = 0;
    while ((R >> s0) >= NB4) s0++;

    int k = topks[row]; if (k < 1) k = 1; if (k > V) k = V;
    const float topp = topps[row];
    const float mp = minps[row];

    // ---- count descent (1-3 levels, fused weight hists for W) ----
    uint32_t lo = base;
    unsigned long long width = (unsigned long long)R + 1ull;
    int s = s0;
    uint32_t tk = (uint32_t)k;
    float Wacc = 0.f;
    uint32_t ukv = base;
    float W = 0.f;
    for (int lvl = 0; ; lvl++) {
        uint32_t* ch = s_cnt;
        float* wh = (lvl == 0) ? s_w0 : s_ww;
        for (int i = tid; i < NB4; i += KTHR) { ch[i] = 0u; wh[i] = 0.f; }
        __syncthreads();
        for (int i = tid; i < n; i += KTHR) {
            uint32_t u = s_u[i];
            if (u >= lo) {
                uint32_t rel = u - lo;
                if ((unsigned long long)rel < width) {
                    int ix = (int)(rel >> s);
                    atomicAdd(&ch[ix], 1u);
                    atomicAdd(&wh[ix], expf(u2f(u)));
                }
            }
        }
        __syncthreads();
        blk_desc_count(ch, tk, s_csU, &sh_bin, &sh_above);
        int b = sh_bin; uint32_t ab = sh_above;
        if (b < 0) { b = 0; ab = 0u; }   // pathological guard
        float part = 0.f;
        for (int i = tid; i < NB4; i += KTHR) if (i > b) part += wh[i];
        Wacc += k4_sum(part, rbf);
        tk = (tk > ab) ? (tk - ab) : 1u;
        lo += (uint32_t)b << s;
        if (s == 0) {
            ukv = lo;
            W = Wacc + wh[b];
            break;
        }
        width = 1ull << s;
        s = (s > 12) ? (s - 12) : 0;
    }
    __syncthreads();
    const float maxw = expf(u2f(umax));
    const float pW = topp * W;

    // ---- top-p boundary ----
    uint32_t up = 0u; float Z2 = W;
    if (!(pW > 0.f)) {
        up = umax - 1u; Z2 = maxw;
    } else {
        uint32_t lop = base;
        unsigned long long widp = (unsigned long long)R + 1ull;
        int sp = s0;
        float Sb = 0.f;
        bool done = false;
        for (int lvl = 0; !done; lvl++) {
            const float* wh;
            if (lvl == 0) {
                wh = s_w0;
            } else {
                for (int i = tid; i < NB4; i += KTHR) s_ww[i] = 0.f;
                __syncthreads();
                for (int i = tid; i < n; i += KTHR) {
                    uint32_t u = s_u[i];
                    if (u >= lop && u >= ukv) {
                        uint32_t rel = u - lop;
                        if ((unsigned long long)rel < widp)
                            atomicAdd(&s_ww[rel >> sp], expf(u2f(u)));
                    }
                }
                __syncthreads();
                wh = s_ww;
            }
            if (sp == 0) blk_desc_wvalue(wh, Sb, pW, s_csF, &sh_bin, &sh_S);
            else         blk_desc_wcross(wh, Sb, pW, s_csF, &sh_bin, &sh_S);
            int b = sh_bin; float Sn = sh_S;
            if (b < 0) {
                up = lop - 1u; Z2 = Sn; done = true;
            } else if (sp == 0) {
                up = lop + (uint32_t)b; Z2 = Sn; done = true;
            } else {
                lop += (uint32_t)b << sp;
                widp = 1ull << sp;
                Sb = Sn;
                sp = (sp > 12) ? (sp - 12) : 0;
            }
            __syncthreads();
        }
        if (up >= umax) { up = umax - 1u; Z2 = maxw; }
        if (up < ukv) Z2 = W;   // vacuous mask -> survivors = all top-k kept
    }

    // ---- min-p + final argmax of w / max(noise,1e-10) (scale-free) ----
    const bool use_mp = (mp > 0.f);
    const float A = use_mp ? (maxw / Z2) * mp : 0.f;

    unsigned long long best = 0ull;
    for (int i = tid; i < n; i += KTHR) {
        uint32_t u = s_u[i];
        if (u >= ukv && u > up) {
            float w = expf(u2f(u));
            if (!(use_mp && (w / Z2) < A)) {
                int idx = s_ix[i];
                float nz = fmaxf(noise[(size_t)row * (size_t)V + idx], 1e-10f);
                float sc = w / nz;
                unsigned long long pk = ((unsigned long long)__float_as_uint(sc) << 32)
                                      | (unsigned long long)(~(uint32_t)idx);
                if (pk > best) best = pk;
            }
        }
    }
    best = k4_max_u64(best, rbq);
    if (tid == 0) out[row] = (int)(~(uint32_t)(best & 0xffffffffull));
}

// ---------------- fallback: monolithic single-kernel path ----------------

#define FNT 1024
#define FNB1 16384
#define FL1SH 18
#define FCAP 8192

static __device__ float fblk_max_f(float v, float* buf) {
    int tid = threadIdx.x;
    buf[tid] = v; __syncthreads();
    for (int o = FNT / 2; o > 0; o >>= 1) {
        if (tid < o) buf[tid] = fmaxf(buf[tid], buf[tid + o]);
        __syncthreads();
    }
    float r = buf[0]; __syncthreads();
    return r;
}
static __device__ float fblk_sum_f(float v, float* buf) {
    int tid = threadIdx.x;
    buf[tid] = v; __syncthreads();
    for (int o = FNT / 2; o > 0; o >>= 1) {
        if (tid < o) buf[tid] += buf[tid + o];
        __syncthreads();
    }
    float r = buf[0]; __syncthreads();
    return r;
}

__global__ __launch_bounds__(FNT, 1) void sampler_fallback_kernel(
    const float* __restrict__ logits, const float* __restrict__ temps,
    const int* __restrict__ topks, const float* __restrict__ topps,
    const float* __restrict__ minps, const float* __restrict__ noise,
    int* __restrict__ out, int V)
{
    __shared__ uint32_t s_hist[FNB1];
    __shared__ uint32_t s_cand[FCAP];
    __shared__ float    s_red[FNT];
    __shared__ uint32_t s_h2[512];
    __shared__ int      sh_bin;
    __shared__ uint32_t sh_above;
    __shared__ int      sh_nc;
    __shared__ int      sh_binw;
    __shared__ float    sh_S;

    const int row = blockIdx.x;
    const int tid = threadIdx.x;
    const int lane = tid & 63;
    const float t  = temps[row];
    const float pp = topps[row];
    const float mp = minps[row];
    int k = topks[row];
    if (k < 1) k = 1;
    if (k > V) k = V;
    const float* lg = logits + (size_t)row * (size_t)V;
    const float* nz = noise  + (size_t)row * (size_t)V;

    for (int i = tid; i < FNB1; i += FNT) s_hist[i] = 0u;
    __syncthreads();

    float lmax = -INFINITY;
    for (int i = tid; i < V; i += FNT) {
        float x = lg[i] / t;
        lmax = fmaxf(lmax, x);
        atomicAdd(&s_hist[f2u(x) >> FL1SH], 1u);
    }
    const float M = fblk_max_f(lmax, s_red);
    const uint32_t umax = f2u(M);
    const int bmax = (int)(umax >> FL1SH);

    if (tid == 0) sh_bin = -1;
    __syncthreads();
    wave_desc_count(s_hist, bmax, 0, (uint32_t)k, &sh_bin, &sh_above);
    __syncthreads();
    const int b1 = sh_bin;
    const uint32_t cntHi = sh_above;

    float* wh = reinterpret_cast<float*>(s_hist);
    for (int i = tid; i < FNB1; i += FNT) wh[i] = 0.f;
    if (tid == 0) sh_nc = 0;
    __syncthreads();
    for (int i = tid; i < V; i += FNT) {
        float x = lg[i] / t;
        uint32_t u = f2u(x);
        atomicAdd(&wh[u >> FL1SH], expf(x - M));
        bool want = ((int)(u >> FL1SH) == b1);
        unsigned long long mb = __ballot(want);
        if (want) {
            int leader = (int)__ffsll(mb) - 1;
            int off = (int)__popcll(mb & ((1ull << lane) - 1ull));
            int bse = 0;
            if (lane == leader) bse = atomicAdd(&sh_nc, (int)__popcll(mb));
            bse = __shfl(bse, leader);
            int p = bse + off;
            if (p < FCAP) s_cand[p] = u;
        }
    }
    __syncthreads();
    int nc = sh_nc; if (nc > FCAP) nc = FCAP;
    const uint32_t kk2 = (uint32_t)k - cntHi;

    for (int i = tid; i < 512; i += FNT) s_h2[i] = 0u;
    __syncthreads();
    for (int i = tid; i < nc; i += FNT) atomicAdd(&s_h2[(s_cand[i] >> 9) & 511u], 1u);
    __syncthreads();
    if (tid == 0) sh_bin = -1;
    __syncthreads();
    wave_desc_count(s_h2, 511, 0, kk2, &sh_bin, &sh_above);
    __syncthreads();
    const int c2 = sh_bin;
    const uint32_t kk3 = kk2 - sh_above;

    for (int i = tid; i < 512; i += FNT) s_h2[i] = 0u;
    __syncthreads();
    for (int i = tid; i < nc; i += FNT) {
        uint32_t u = s_cand[i];
        if ((int)((u >> 9) & 511u) == c2) atomicAdd(&s_h2[u & 511u], 1u);
    }
    __syncthreads();
    if (tid == 0) sh_bin = -1;
    __syncthreads();
    wave_desc_count(s_h2, 511, 0, kk3, &sh_bin, &sh_above);
    __syncthreads();
    const uint32_t uk = ((uint32_t)b1 << FL1SH) | ((uint32_t)c2 << 9) | (uint32_t)sh_bin;

    float wl = 0.f;
    for (int i = tid; i < nc; i += FNT) {
        uint32_t u = s_cand[i];
        if (u >= uk) wl += expf(u2f(u) - M);
    }
    const float Wb1 = fblk_sum_f(wl, s_red);
    if (tid == 0) wh[b1] = Wb1;
    __syncthreads();
    float sl = 0.f;
    for (int i = tid; i < FNB1; i += FNT)
        if (i >= b1 && i <= bmax) sl += wh[i];
    const float W = fblk_sum_f(sl, s_red);
    const float pW = pp * W;

    uint32_t up = 0u;
    float Z2 = W;
    if (pW <= 0.f) {
        up = umax - 1u;
        Z2 = 1.0f;
    } else {
        if (tid == 0) sh_binw = -1;
        __syncthreads();
        wave_desc_wcross(wh, bmax, b1, 0.f, pW, &sh_binw, &sh_S);
        __syncthreads();
        const int cs = sh_binw;
        if (cs >= 0) {
            const float S1 = sh_S;
            if (cs != b1) {
                if (tid == 0) sh_nc = 0;
                __syncthreads();
                for (int i = tid; i < V; i += FNT) {
                    float x = lg[i] / t;
                    uint32_t u = f2u(x);
                    bool want = (u >= uk) && ((int)(u >> FL1SH) == cs);
                    unsigned long long mb = __ballot(want);
                    if (want) {
                        int leader = (int)__ffsll(mb) - 1;
                        int off = (int)__popcll(mb & ((1ull << lane) - 1ull));
                        int bse = 0;
                        if (lane == leader) bse = atomicAdd(&sh_nc, (int)__popcll(mb));
                        bse = __shfl(bse, leader);
                        int p = bse + off;
                        if (p < FCAP) s_cand[p] = u;
                    }
                }
                __syncthreads();
                nc = sh_nc; if (nc > FCAP) nc = FCAP;
            }
            float* wh2 = reinterpret_cast<float*>(s_h2);
            for (int i = tid; i < 512; i += FNT) wh2[i] = 0.f;
            __syncthreads();
            for (int i = tid; i < nc; i += FNT) {
                uint32_t u = s_cand[i];
                if (u >= uk) atomicAdd(&wh2[(u >> 9) & 511u], expf(u2f(u) - M));
            }
            __syncthreads();
            if (tid == 0) sh_binw = -1;
            __syncthreads();
            wave_desc_wcross(wh2, 511, 0, S1, pW, &sh_binw, &sh_S);
            __syncthreads();
            const int c2p = sh_binw;
            if (c2p < 0) {
                uint32_t basev = (uint32_t)cs << FL1SH;
                up = basev ? basev - 1u : 0u;
                Z2 = sh_S;
            } else {
                const float S2 = sh_S;
                for (int i = tid; i < 512; i += FNT) wh2[i] = 0.f;
                __syncthreads();
                for (int i = tid; i < nc; i += FNT) {
                    uint32_t u = s_cand[i];
                    if (u >= uk && (int)((u >> 9) & 511u) == c2p)
                        atomicAdd(&wh2[u & 511u], expf(u2f(u) - M));
                }
                __syncthreads();
                if (tid == 0) sh_binw = -1;
                __syncthreads();
                wave_desc_wvalue(wh2, 511, 0, S2, pW, &sh_binw, &sh_S);
                __syncthreads();
                if (sh_binw < 0) {
                    uint32_t basev = ((uint32_t)cs << FL1SH) | ((uint32_t)c2p << 9);
                    up = basev ? basev - 1u : 0u;
                    Z2 = sh_S;
                } else {
                    up = ((uint32_t)cs << FL1SH) | ((uint32_t)c2p << 9) | (uint32_t)sh_binw;
                    Z2 = sh_S;
                }
            }
        }
        if (up >= umax) { up = umax - 1u; Z2 = 1.0f; }
    }
    __syncthreads();

    const bool use_mp = (mp > 0.f);
    const float thr = mp * (1.0f / Z2);

    float zl = 0.f;
    for (int i = tid; i < V; i += FNT) {
        float x = lg[i] / t;
        uint32_t u = f2u(x);
        if (u >= uk && u > up) {
            float w = expf(x - M);
            if (use_mp && (w / Z2) < thr) continue;
            zl += w;
        }
    }
    const float Z3 = fblk_sum_f(zl, s_red);

    float bs = -1.f; int bi = 0x7fffffff;
    for (int i = tid; i < V; i += FNT) {
        float x = lg[i] / t;
        uint32_t u = f2u(x);
        if (u >= uk && u > up) {
            float w = expf(x - M);
            if (use_mp && (w / Z2) < thr) continue;
            float sc = (w / Z3) / fmaxf(nz[i], 1e-10f);
            if (sc > bs) { bs = sc; bi = i; }
        }
    }
    s_red[tid] = bs;
    int* ibuf = reinterpret_cast<int*>(s_cand);
    ibuf[tid] = bi;
    __syncthreads();
    for (int o = FNT / 2; o > 0; o >>= 1) {
        if (tid < o) {
            float v2 = s_red[tid + o]; int i2 = ibuf[tid + o];
            if (v2 > s_red[tid] || (v2 == s_red[tid] && i2 < ibuf[tid])) {
                s_red[tid] = v2; ibuf[tid] = i2;
            }
        }
        __syncthreads();
    }
    if (tid == 0) out[row] = ibuf[0];
}

// ---------------- launch ----------------

extern "C" void kernel_launch(void* const* d_in, const int* in_sizes, int n_in,
                              void* d_out, int out_size, void* d_ws, size_t ws_size,
                              hipStream_t stream) {
    const float* logits = (const float*)d_in[0];
    const float* temps  = (const float*)d_in[1];
    const int*   topks  = (const int*)d_in[2];
    const float* topps  = (const float*)d_in[3];
    const float* minps  = (const float*)d_in[4];
    const float* noise  = (const float*)d_in[5];
    const int B = in_sizes[1];
    const int V = in_sizes[0] / B;
    int* out = (int*)d_out;

    const int sliceLen = (((V + SLICES - 1) / SLICES) + 1023) & ~1023;

    const size_t offCU  = 0;
    const size_t offCI  = offCU + (size_t)B * SLICES * SUBCAP * 4;
    const size_t offCnt = offCI + (size_t)B * SLICES * SUBCAP * 4;
    const size_t need   = offCnt + (size_t)B * SLICES * 4;

    if (ws_size >= need && (V & 3) == 0 && (size_t)SLICES * (size_t)sliceLen >= (size_t)V) {
        char* ws = (char*)d_ws;
        uint32_t* cand_u  = (uint32_t*)(ws + offCU);
        int*      cand_ix = (int*)(ws + offCI);
        uint32_t* candCnt = (uint32_t*)(ws + offCnt);

        dim3 gslice(SLICES, B);
        k1_collect<<<gslice, K1T, 0, stream>>>(logits, temps, cand_u, cand_ix, candCnt, V, sliceLen);
        k4_final<<<B, KTHR, 0, stream>>>(topks, topps, minps, noise, candCnt, cand_u, cand_ix, out, V);
    } else {
        sampler_fallback_kernel<<<B, FNT, 0, stream>>>(logits, temps, topks, topps, minps, noise, out, V);
    }
}

// Round 5
// 95.935 us; speedup vs baseline: 3.9959x; 3.9959x over previous
//
#include <hip/hip_runtime.h>
#include <cstdint>
#include <cmath>

// ---------------- tunables ----------------
#define SLICES 16
#define SUBCAP 384
#define CAPT (SLICES * SUBCAP)   // 6144
#define KT4 256                  // k4 block size
#define K1T 256                  // k1 block size
#define THRC 1.9f                // k1 collect threshold = mu + THRC*sigma

// order-preserving float<->uint bijection
static __device__ __forceinline__ uint32_t f2u(float f) {
    uint32_t b = __float_as_uint(f);
    return (b & 0x80000000u) ? ~b : (b | 0x80000000u);
}
static __device__ __forceinline__ float u2f(uint32_t u) {
    uint32_t b = (u & 0x80000000u) ? (u ^ 0x80000000u) : ~u;
    return __uint_as_float(b);
}

static __device__ __forceinline__ uint32_t wave_incl_u(uint32_t v) {
    int lane = threadIdx.x & 63;
#pragma unroll
    for (int o = 1; o < 64; o <<= 1) {
        uint32_t t = __shfl_up(v, (unsigned)o);
        if (lane >= o) v += t;
    }
    return v;
}
static __device__ __forceinline__ float wave_incl_f(float v) {
    int lane = threadIdx.x & 63;
#pragma unroll
    for (int o = 1; o < 64; o <<= 1) {
        float t = __shfl_up(v, (unsigned)o);
        if (lane >= o) v += t;
    }
    return v;
}

// ---------- 1024-bin descending wave descents (wave 0 only; 16 fixed rounds,
// NO serial walks — round-4 lesson) ----------

// counts: first bin b (desc) with above < target <= above + h[b]
static __device__ void d1024_count(const uint32_t* __restrict__ h, uint32_t target,
                                   int* out_bin, uint32_t* out_above) {
    if (threadIdx.x < 64) {
        const int lane = threadIdx.x;
        uint32_t S = 0;
        for (int r0 = 1023; r0 >= 0; r0 -= 64) {
            int b = r0 - lane;
            uint32_t w = h[b];
            uint32_t incl = wave_incl_u(w);
            uint32_t Sb = S + incl - w;
            bool cross = (Sb < target) && (Sb + w >= target);
            unsigned long long m = __ballot(cross);
            if (m) {
                int l = (int)__ffsll(m) - 1;
                if (lane == l) { *out_bin = b; *out_above = Sb; }
                return;
            }
            S += __shfl(incl, 63);
        }
        if (lane == 0) { *out_bin = -1; *out_above = S; }
    }
}
// weighted crossing vs ABSOLUTE target (running base Sbase)
static __device__ void d1024_wcross(const float* __restrict__ h, float Sbase, float target,
                                    int* out_bin, float* out_S) {
    if (threadIdx.x < 64) {
        const int lane = threadIdx.x;
        float S = Sbase;
        for (int r0 = 1023; r0 >= 0; r0 -= 64) {
            int b = r0 - lane;
            float w = h[b];
            float incl = wave_incl_f(w);
            float Sb = S + (incl - w);
            bool cross = (Sb < target) && (Sb + w >= target);
            unsigned long long m = __ballot(cross);
            if (m) {
                int l = (int)__ffsll(m) - 1;
                if (lane == l) { *out_bin = b; *out_S = Sb; }
                return;
            }
            S += __shfl(incl, 63);
        }
        if (lane == 0) { *out_bin = -1; *out_S = S; }
    }
}
// weighted VALUE rule: first nonempty bin (desc) with strict-suffix >= target
static __device__ void d1024_wvalue(const float* __restrict__ h, float Sbase, float target,
                                    int* out_bin, float* out_S) {
    if (threadIdx.x < 64) {
        const int lane = threadIdx.x;
        float S = Sbase;
        for (int r0 = 1023; r0 >= 0; r0 -= 64) {
            int b = r0 - lane;
            float w = h[b];
            float incl = wave_incl_f(w);
            float Sb = S + (incl - w);
            bool cross = (w > 0.f) && (Sb >= target);
            unsigned long long m = __ballot(cross);
            if (m) {
                int l = (int)__ffsll(m) - 1;
                if (lane == l) { *out_bin = b; *out_S = Sb; }
                return;
            }
            S += __shfl(incl, 63);
        }
        if (lane == 0) { *out_bin = -1; *out_S = S; }
    }
}

// ---------- 256-thread (4-wave) block reductions ----------
static __device__ __forceinline__ unsigned long long shflxor_u64(unsigned long long v, int o) {
    uint32_t lo = (uint32_t)v, hi = (uint32_t)(v >> 32);
    lo = __shfl_xor(lo, o); hi = __shfl_xor(hi, o);
    return ((unsigned long long)hi << 32) | (unsigned long long)lo;
}
static __device__ float blk_sum(float v, float* rb) {
#pragma unroll
    for (int o = 32; o > 0; o >>= 1) v += __shfl_xor(v, o);
    const int wv = threadIdx.x >> 6;
    if ((threadIdx.x & 63) == 0) rb[wv] = v;
    __syncthreads();
    float r = (threadIdx.x < 4) ? rb[threadIdx.x] : 0.f;
    if (threadIdx.x < 64) {
#pragma unroll
        for (int o = 2; o > 0; o >>= 1) r += __shfl_xor(r, o);
        if (threadIdx.x == 0) rb[0] = r;
    }
    __syncthreads();
    r = rb[0];
    __syncthreads();
    return r;
}
static __device__ uint32_t blk_max_u32(uint32_t v, uint32_t* rb) {
#pragma unroll
    for (int o = 32; o > 0; o >>= 1) { uint32_t x = __shfl_xor(v, o); if (x > v) v = x; }
    const int wv = threadIdx.x >> 6;
    if ((threadIdx.x & 63) == 0) rb[wv] = v;
    __syncthreads();
    uint32_t r = (threadIdx.x < 4) ? rb[threadIdx.x] : 0u;
    if (threadIdx.x < 64) {
#pragma unroll
        for (int o = 2; o > 0; o >>= 1) { uint32_t x = __shfl_xor(r, o); if (x > r) r = x; }
        if (threadIdx.x == 0) rb[0] = r;
    }
    __syncthreads();
    r = rb[0];
    __syncthreads();
    return r;
}
static __device__ uint32_t blk_min_u32(uint32_t v, uint32_t* rb) {
#pragma unroll
    for (int o = 32; o > 0; o >>= 1) { uint32_t x = __shfl_xor(v, o); if (x < v) v = x; }
    const int wv = threadIdx.x >> 6;
    if ((threadIdx.x & 63) == 0) rb[wv] = v;
    __syncthreads();
    uint32_t r = (threadIdx.x < 4) ? rb[threadIdx.x] : 0xFFFFFFFFu;
    if (threadIdx.x < 64) {
#pragma unroll
        for (int o = 2; o > 0; o >>= 1) { uint32_t x = __shfl_xor(r, o); if (x < r) r = x; }
        if (threadIdx.x == 0) rb[0] = r;
    }
    __syncthreads();
    r = rb[0];
    __syncthreads();
    return r;
}
static __device__ unsigned long long blk_max_u64(unsigned long long v, unsigned long long* rb) {
#pragma unroll
    for (int o = 32; o > 0; o >>= 1) { unsigned long long x = shflxor_u64(v, o); if (x > v) v = x; }
    const int wv = threadIdx.x >> 6;
    if ((threadIdx.x & 63) == 0) rb[wv] = v;
    __syncthreads();
    unsigned long long r = (threadIdx.x < 4) ? rb[threadIdx.x] : 0ull;
    if (threadIdx.x < 64) {
#pragma unroll
        for (int o = 2; o > 0; o >>= 1) { unsigned long long x = shflxor_u64(r, o); if (x > r) r = x; }
        if (threadIdx.x == 0) rb[0] = r;
    }
    __syncthreads();
    r = rb[0];
    __syncthreads();
    return r;
}

// ---------------- K1: stats-threshold collect (single HBM pass + L2-hot re-read) ----------------

__global__ __launch_bounds__(K1T) void k1_collect(
    const float* __restrict__ logits, const float* __restrict__ temps,
    uint32_t* __restrict__ cand_u, int* __restrict__ cand_ix,
    uint32_t* __restrict__ candCnt, int V, int sliceLen)
{
    const int row = blockIdx.y, slice = blockIdx.x, tid = threadIdx.x;
    const int lane = tid & 63, wv = tid >> 6;
    __shared__ float redm[4], reds[4], redq[4];
    __shared__ float s_thr;
    __shared__ int wsum[4];
    __shared__ int s_base;

    const int base = slice * sliceLen;
    int len = V - base;
    if (len > sliceLen) len = sliceLen;
    if (len <= 0) { if (tid == 0) candCnt[row * SLICES + slice] = 0u; return; }

    const float* lg = logits + (size_t)row * (size_t)V;
    const float4* p4 = (const float4*)(lg + base);
    const int n4 = len >> 2;

    // pass 1: raw-logit stats (max, sum, sumsq)
    float mx = -INFINITY, sm = 0.f, sq = 0.f;
    for (int i = tid; i < n4; i += K1T) {
        float4 v = p4[i];
        mx = fmaxf(mx, fmaxf(fmaxf(v.x, v.y), fmaxf(v.z, v.w)));
        sm += (v.x + v.y) + (v.z + v.w);
        sq += (v.x * v.x + v.y * v.y) + (v.z * v.z + v.w * v.w);
    }
#pragma unroll
    for (int o = 32; o > 0; o >>= 1) {
        mx = fmaxf(mx, __shfl_xor(mx, o));
        sm += __shfl_xor(sm, o);
        sq += __shfl_xor(sq, o);
    }
    if (lane == 0) { redm[wv] = mx; reds[wv] = sm; redq[wv] = sq; }
    __syncthreads();
    if (tid == 0) {
        float m = redm[0], s = reds[0], q = redq[0];
        for (int w = 1; w < 4; w++) { m = fmaxf(m, redm[w]); s += reds[w]; q += redq[w]; }
        float inv = 1.f / (float)len;
        float mu = s * inv;
        float var = fmaxf(q * inv - mu * mu, 0.f);
        float thr = mu + THRC * sqrtf(var);
        if (thr > m) thr = m;   // always keep at least the slice max
        s_thr = thr;
        s_base = 0;
    }
    __syncthreads();
    const float thr = s_thr;
    const float t = temps[row];
    uint32_t* cu = cand_u + ((size_t)row * SLICES + slice) * SUBCAP;
    int* cix = cand_ix + ((size_t)row * SLICES + slice) * SUBCAP;

    // pass 2: deterministic compaction of raw a >= thr ; store u = f2u(a/t)
    for (int c0 = 0; c0 < len; c0 += K1T * 4) {
        const int i0 = c0 + tid * 4;
        bool k0 = false, k1b = false, k2b = false, k3b = false;
        float4 v = make_float4(0.f, 0.f, 0.f, 0.f);
        if (i0 < len) {   // len % 4 == 0 -> all four valid
            v = *(const float4*)(lg + base + i0);
            k0 = (v.x >= thr); k1b = (v.y >= thr); k2b = (v.z >= thr); k3b = (v.w >= thr);
        }
        int cnt = (int)k0 + (int)k1b + (int)k2b + (int)k3b;
        int inc = cnt;
#pragma unroll
        for (int o = 1; o < 64; o <<= 1) {
            int x = __shfl_up(inc, (unsigned)o);
            if (lane >= o) inc += x;
        }
        if (lane == 63) wsum[wv] = inc;
        __syncthreads();
        int woff = 0;
        for (int w = 0; w < wv; w++) woff += wsum[w];
        const int tot = wsum[0] + wsum[1] + wsum[2] + wsum[3];
        int p = s_base + woff + inc - cnt;
        if (k0)  { if (p < SUBCAP) { cu[p] = f2u(v.x / t); cix[p] = base + i0;     } p++; }
        if (k1b) { if (p < SUBCAP) { cu[p] = f2u(v.y / t); cix[p] = base + i0 + 1; } p++; }
        if (k2b) { if (p < SUBCAP) { cu[p] = f2u(v.z / t); cix[p] = base + i0 + 2; } p++; }
        if (k3b) { if (p < SUBCAP) { cu[p] = f2u(v.w / t); cix[p] = base + i0 + 3; } p++; }
        __syncthreads();
        if (tid == 0) s_base += tot;
        __syncthreads();
    }
    if (tid == 0) {
        int c = s_base; if (c > SUBCAP) c = SUBCAP;
        candCnt[row * SLICES + slice] = (uint32_t)c;
    }
}

// ---------------- K4: per-row finalize over <=6144 candidates ----------------
// 256 threads, 1024-bin prefix-skip radix descents, Z2/Z3-free epilogue.

__global__ __launch_bounds__(KT4, 2) void k4_final(
    const int* __restrict__ topks, const float* __restrict__ topps,
    const float* __restrict__ minps, const float* __restrict__ noise,
    const uint32_t* __restrict__ candCnt, const uint32_t* __restrict__ cand_u,
    const int* __restrict__ cand_ix, int* __restrict__ out, int V)
{
    const int row = blockIdx.x, tid = threadIdx.x;
    __shared__ uint32_t s_u[CAPT];
    __shared__ int s_ix[CAPT];
    __shared__ uint32_t s_hc[1024];     // count hist; aliased as float for weighted
    __shared__ int s_off[SLICES + 1];
    __shared__ uint32_t rbu[4];
    __shared__ float rbf[4];
    __shared__ unsigned long long rbq[4];
    __shared__ int sh_bin; __shared__ uint32_t sh_above; __shared__ float sh_S;

    if (tid == 0) {
        int a = 0;
        for (int s = 0; s < SLICES; s++) {
            s_off[s] = a;
            int c = (int)candCnt[row * SLICES + s];
            if (c > SUBCAP) c = SUBCAP;
            a += c;
        }
        s_off[SLICES] = a;
    }
    __syncthreads();
    const int n = s_off[SLICES];
    uint32_t um = 0u, un = 0xFFFFFFFFu;
    for (int s = 0; s < SLICES; s++) {
        const int o0 = s_off[s], c = s_off[s + 1] - o0;
        const size_t gb = ((size_t)row * SLICES + s) * SUBCAP;
        for (int j = tid; j < c; j += KT4) {
            uint32_t u = cand_u[gb + j];
            s_u[o0 + j] = u;
            s_ix[o0 + j] = cand_ix[gb + j];
            if (u > um) um = u;
            if (u < un) un = u;
        }
    }
    __syncthreads();
    const uint32_t umax = blk_max_u32(um, rbu);
    const uint32_t base = blk_min_u32(un, rbu);
    const uint32_t diff = umax ^ base;
    const int hb = (diff == 0u) ? 0 : (31 - __clz(diff));
    int sh0 = hb - 9; if (sh0 < 0) sh0 = 0;

    int k = topks[row]; if (k < 1) k = 1; if (k > V) k = V;

    // ---- exact top-k threshold value uk: 1024-bin prefix-skip count descent ----
    uint32_t selHi = (sh0 + 10 >= 32) ? 0u : (base >> (sh0 + 10));
    int sh = sh0, shPrev = sh0 + 10;
    uint32_t tk = (uint32_t)k;
    for (int lvl = 0; ; lvl++) {
        for (int i = tid; i < 1024; i += KT4) s_hc[i] = 0u;
        __syncthreads();
        for (int i = tid; i < n; i += KT4) {
            uint32_t u = s_u[i];
            if (lvl == 0 || (u >> shPrev) == selHi)
                atomicAdd(&s_hc[(u >> sh) & 1023u], 1u);
        }
        __syncthreads();
        d1024_count(s_hc, tk, &sh_bin, &sh_above);
        __syncthreads();
        int b = sh_bin;
        uint32_t ab = sh_above;
        if (b < 0) { b = 0; ab = 0u; }   // pathological guard (k > n)
        tk = (tk > ab) ? (tk - ab) : 1u;
        int step = shPrev - sh; if (step > 10) step = 10;
        selHi = (selHi << step) | ((uint32_t)b & ((1u << step) - 1u));
        if (sh == 0) break;
        shPrev = sh;
        sh = (sh >= 10) ? (sh - 10) : 0;
    }
    const uint32_t uk = selHi;

    // ---- W over kept (single reduction) ----
    float wl = 0.f;
    for (int i = tid; i < n; i += KT4) { uint32_t u = s_u[i]; if (u >= uk) wl += expf(u2f(u)); }
    const float W = blk_sum(wl, rbf);
    const float pW = topps[row] * W;
    const float maxw = expf(u2f(umax));

    // ---- top-p boundary value up (mask kept u <= up); Z2 not needed ----
    uint32_t up = 0u;
    if (!(pW > 0.f)) {
        up = umax - 1u;   // p == 0: keep only the max
    } else {
        float* fw = (float*)s_hc;
        uint32_t selP = (sh0 + 10 >= 32) ? 0u : (base >> (sh0 + 10));
        int shp = sh0, shPv = sh0 + 10;
        float Sb = 0.f;
        for (int lvl = 0; ; lvl++) {
            for (int i = tid; i < 1024; i += KT4) fw[i] = 0.f;
            __syncthreads();
            for (int i = tid; i < n; i += KT4) {
                uint32_t u = s_u[i];
                if (u >= uk && (lvl == 0 || (u >> shPv) == selP))
                    atomicAdd(&fw[(u >> shp) & 1023u], expf(u2f(u)));
            }
            __syncthreads();
            if (shp == 0) d1024_wvalue(fw, Sb, pW, &sh_bin, &sh_S);
            else          d1024_wcross(fw, Sb, pW, &sh_bin, &sh_S);
            __syncthreads();
            const int b = sh_bin;
            if (b < 0) {
                // suffix never reaches pW within this class: mask everything strictly below it
                up = (lvl == 0) ? 0u : ((selP << shPv) - 1u);
                break;
            }
            int step = shPv - shp; if (step > 10) step = 10;
            selP = (selP << step) | ((uint32_t)b & ((1u << step) - 1u));
            if (shp == 0) { up = selP; break; }   // exact boundary value
            Sb = sh_S;
            shPv = shp;
            shp = (shp >= 10) ? (shp - 10) : 0;
        }
        if (up >= umax) up = umax - 1u;   // never mask the max
    }
    __syncthreads();

    // ---- min-p (Z2 cancels: probs < maxprob*mp  <=>  w < maxw*mp) + scale-free argmax ----
    const float mp = minps[row];
    const bool use_mp = (mp > 0.f);
    const float A = mp * maxw;

    unsigned long long best = 0ull;
    for (int i = tid; i < n; i += KT4) {
        uint32_t u = s_u[i];
        if (u >= uk && u > up) {
            float w = expf(u2f(u));
            if (!(use_mp && w < A)) {
                int idx = s_ix[i];
                float nz = fmaxf(noise[(size_t)row * (size_t)V + idx], 1e-10f);
                float sc = w / nz;
                unsigned long long pk = ((unsigned long long)__float_as_uint(sc) << 32)
                                      | (unsigned long long)(~(uint32_t)idx);
                if (pk > best) best = pk;
            }
        }
    }
    best = blk_max_u64(best, rbq);
    if (tid == 0) out[row] = (int)(~(uint32_t)(best & 0xffffffffull));
}

// ---------------- fallback: monolithic single-kernel path ----------------

#define FNT 1024
#define FNB1 16384
#define FL1SH 18
#define FCAP 8192

static __device__ void wave_desc_count_f(const uint32_t* h, int hi, int lo, uint32_t target,
                                         int* out_bin, uint32_t* out_above) {
    if (threadIdx.x < 64) {
        int lane = threadIdx.x;
        uint32_t S = 0;
        for (int r0 = hi; r0 >= lo; r0 -= 64) {
            int b = r0 - lane;
            uint32_t w = (b >= lo) ? h[b] : 0u;
            uint32_t incl = wave_incl_u(w);
            uint32_t Sb = S + incl - w;
            bool cross = (Sb < target) && (Sb + w >= target);
            unsigned long long m = __ballot(cross);
            if (m) {
                int l = (int)__ffsll(m) - 1;
                if (lane == l) { *out_bin = b; *out_above = Sb; }
                return;
            }
            S += __shfl(incl, 63);
        }
        if (lane == 0) { *out_bin = -1; *out_above = S; }
    }
}
static __device__ void wave_desc_wcross_f(const float* h, int hi, int lo, float base, float target,
                                          int* out_bin, float* out_S) {
    if (threadIdx.x < 64) {
        int lane = threadIdx.x;
        float S = base;
        for (int r0 = hi; r0 >= lo; r0 -= 64) {
            int b = r0 - lane;
            float w = (b >= lo) ? h[b] : 0.f;
            float incl = wave_incl_f(w);
            float Sb = S + (incl - w);
            bool cross = (Sb < target) && (Sb + w >= target);
            unsigned long long m = __ballot(cross);
            if (m) {
                int l = (int)__ffsll(m) - 1;
                if (lane == l) { *out_bin = b; *out_S = Sb; }
                return;
            }
            S += __shfl(incl, 63);
        }
        if (lane == 0) { *out_bin = -1; *out_S = S; }
    }
}
static __device__ void wave_desc_wvalue_f(const float* h, int hi, int lo, float base, float target,
                                          int* out_bin, float* out_S) {
    if (threadIdx.x < 64) {
        int lane = threadIdx.x;
        float S = base;
        for (int r0 = hi; r0 >= lo; r0 -= 64) {
            int b = r0 - lane;
            float w = (b >= lo) ? h[b] : 0.f;
            float incl = wave_incl_f(w);
            float Sb = S + (incl - w);
            bool cross = (w > 0.f) && (Sb >= target);
            unsigned long long m = __ballot(cross);
            if (m) {
                int l = (int)__ffsll(m) - 1;
                if (lane == l) { *out_bin = b; *out_S = Sb; }
                return;
            }
            S += __shfl(incl, 63);
        }
        if (lane == 0) { *out_bin = -1; *out_S = S; }
    }
}

static __device__ float fblk_max_f(float v, float* buf) {
    int tid = threadIdx.x;
    buf[tid] = v; __syncthreads();
    for (int o = FNT / 2; o > 0; o >>= 1) {
        if (tid < o) buf[tid] = fmaxf(buf[tid], buf[tid + o]);
        __syncthreads();
    }
    float r = buf[0]; __syncthreads();
    return r;
}
static __device__ float fblk_sum_f(float v, float* buf) {
    int tid = threadIdx.x;
    buf[tid] = v; __syncthreads();
    for (int o = FNT / 2; o > 0; o >>= 1) {
        if (tid < o) buf[tid] += buf[tid + o];
        __syncthreads();
    }
    float r = buf[0]; __syncthreads();
    return r;
}

__global__ __launch_bounds__(FNT, 1) void sampler_fallback_kernel(
    const float* __restrict__ logits, const float* __restrict__ temps,
    const int* __restrict__ topks, const float* __restrict__ topps,
    const float* __restrict__ minps, const float* __restrict__ noise,
    int* __restrict__ out, int V)
{
    __shared__ uint32_t s_hist[FNB1];
    __shared__ uint32_t s_cand[FCAP];
    __shared__ float    s_red[FNT];
    __shared__ uint32_t s_h2[512];
    __shared__ int      sh_bin;
    __shared__ uint32_t sh_above;
    __shared__ int      sh_nc;
    __shared__ int      sh_binw;
    __shared__ float    sh_S;

    const int row = blockIdx.x;
    const int tid = threadIdx.x;
    const int lane = tid & 63;
    const float t  = temps[row];
    const float pp = topps[row];
    const float mp = minps[row];
    int k = topks[row];
    if (k < 1) k = 1;
    if (k > V) k = V;
    const float* lg = logits + (size_t)row * (size_t)V;
    const float* nz = noise  + (size_t)row * (size_t)V;

    for (int i = tid; i < FNB1; i += FNT) s_hist[i] = 0u;
    __syncthreads();

    float lmax = -INFINITY;
    for (int i = tid; i < V; i += FNT) {
        float x = lg[i] / t;
        lmax = fmaxf(lmax, x);
        atomicAdd(&s_hist[f2u(x) >> FL1SH], 1u);
    }
    const float M = fblk_max_f(lmax, s_red);
    const uint32_t umax = f2u(M);
    const int bmax = (int)(umax >> FL1SH);

    wave_desc_count_f(s_hist, bmax, 0, (uint32_t)k, &sh_bin, &sh_above);
    __syncthreads();
    const int b1 = sh_bin;
    const uint32_t cntHi = sh_above;

    float* wh = reinterpret_cast<float*>(s_hist);
    for (int i = tid; i < FNB1; i += FNT) wh[i] = 0.f;
    if (tid == 0) sh_nc = 0;
    __syncthreads();
    for (int i = tid; i < V; i += FNT) {
        float x = lg[i] / t;
        uint32_t u = f2u(x);
        atomicAdd(&wh[u >> FL1SH], expf(x - M));
        bool want = ((int)(u >> FL1SH) == b1);
        unsigned long long mb = __ballot(want);
        if (want) {
            int leader = (int)__ffsll(mb) - 1;
            int off = (int)__popcll(mb & ((1ull << lane) - 1ull));
            int bse = 0;
            if (lane == leader) bse = atomicAdd(&sh_nc, (int)__popcll(mb));
            bse = __shfl(bse, leader);
            int p = bse + off;
            if (p < FCAP) s_cand[p] = u;
        }
    }
    __syncthreads();
    int nc = sh_nc; if (nc > FCAP) nc = FCAP;
    const uint32_t kk2 = (uint32_t)k - cntHi;

    for (int i = tid; i < 512; i += FNT) s_h2[i] = 0u;
    __syncthreads();
    for (int i = tid; i < nc; i += FNT) atomicAdd(&s_h2[(s_cand[i] >> 9) & 511u], 1u);
    __syncthreads();
    wave_desc_count_f(s_h2, 511, 0, kk2, &sh_bin, &sh_above);
    __syncthreads();
    const int c2 = sh_bin;
    const uint32_t kk3 = kk2 - sh_above;

    for (int i = tid; i < 512; i += FNT) s_h2[i] = 0u;
    __syncthreads();
    for (int i = tid; i < nc; i += FNT) {
        uint32_t u = s_cand[i];
        if ((int)((u >> 9) & 511u) == c2) atomicAdd(&s_h2[u & 511u], 1u);
    }
    __syncthreads();
    wave_desc_count_f(s_h2, 511, 0, kk3, &sh_bin, &sh_above);
    __syncthreads();
    const uint32_t uk = ((uint32_t)b1 << FL1SH) | ((uint32_t)c2 << 9) | (uint32_t)sh_bin;

    float wl = 0.f;
    for (int i = tid; i < nc; i += FNT) {
        uint32_t u = s_cand[i];
        if (u >= uk) wl += expf(u2f(u) - M);
    }
    const float Wb1 = fblk_sum_f(wl, s_red);
    if (tid == 0) wh[b1] = Wb1;
    __syncthreads();
    float sl = 0.f;
    for (int i = tid; i < FNB1; i += FNT)
        if (i >= b1 && i <= bmax) sl += wh[i];
    const float W = fblk_sum_f(sl, s_red);
    const float pW = pp * W;

    uint32_t up = 0u;
    float Z2 = W;
    if (pW <= 0.f) {
        up = umax - 1u;
        Z2 = 1.0f;
    } else {
        wave_desc_wcross_f(wh, bmax, b1, 0.f, pW, &sh_binw, &sh_S);
        __syncthreads();
        const int cs = sh_binw;
        if (cs >= 0) {
            const float S1 = sh_S;
            if (cs != b1) {
                if (tid == 0) sh_nc = 0;
                __syncthreads();
                for (int i = tid; i < V; i += FNT) {
                    float x = lg[i] / t;
                    uint32_t u = f2u(x);
                    bool want = (u >= uk) && ((int)(u >> FL1SH) == cs);
                    unsigned long long mb = __ballot(want);
                    if (want) {
                        int leader = (int)__ffsll(mb) - 1;
                        int off = (int)__popcll(mb & ((1ull << lane) - 1ull));
                        int bse = 0;
                        if (lane == leader) bse = atomicAdd(&sh_nc, (int)__popcll(mb));
                        bse = __shfl(bse, leader);
                        int p = bse + off;
                        if (p < FCAP) s_cand[p] = u;
                    }
                }
                __syncthreads();
                nc = sh_nc; if (nc > FCAP) nc = FCAP;
            }
            float* wh2 = reinterpret_cast<float*>(s_h2);
            for (int i = tid; i < 512; i += FNT) wh2[i] = 0.f;
            __syncthreads();
            for (int i = tid; i < nc; i += FNT) {
                uint32_t u = s_cand[i];
                if (u >= uk) atomicAdd(&wh2[(u >> 9) & 511u], expf(u2f(u) - M));
            }
            __syncthreads();
            wave_desc_wcross_f(wh2, 511, 0, S1, pW, &sh_binw, &sh_S);
            __syncthreads();
            const int c2p = sh_binw;
            if (c2p < 0) {
                uint32_t basev = (uint32_t)cs << FL1SH;
                up = basev ? basev - 1u : 0u;
                Z2 = sh_S;
            } else {
                const float S2 = sh_S;
                for (int i = tid; i < 512; i += FNT) wh2[i] = 0.f;
                __syncthreads();
                for (int i = tid; i < nc; i += FNT) {
                    uint32_t u = s_cand[i];
                    if (u >= uk && (int)((u >> 9) & 511u) == c2p)
                        atomicAdd(&wh2[u & 511u], expf(u2f(u) - M));
                }
                __syncthreads();
                wave_desc_wvalue_f(wh2, 511, 0, S2, pW, &sh_binw, &sh_S);
                __syncthreads();
                if (sh_binw < 0) {
                    uint32_t basev = ((uint32_t)cs << FL1SH) | ((uint32_t)c2p << 9);
                    up = basev ? basev - 1u : 0u;
                    Z2 = sh_S;
                } else {
                    up = ((uint32_t)cs << FL1SH) | ((uint32_t)c2p << 9) | (uint32_t)sh_binw;
                    Z2 = sh_S;
                }
            }
        }
        if (up >= umax) { up = umax - 1u; Z2 = 1.0f; }
    }
    __syncthreads();

    const bool use_mp = (mp > 0.f);
    const float thr = mp * (1.0f / Z2);

    float zl = 0.f;
    for (int i = tid; i < V; i += FNT) {
        float x = lg[i] / t;
        uint32_t u = f2u(x);
        if (u >= uk && u > up) {
            float w = expf(x - M);
            if (use_mp && (w / Z2) < thr) continue;
            zl += w;
        }
    }
    const float Z3 = fblk_sum_f(zl, s_red);

    float bs = -1.f; int bi = 0x7fffffff;
    for (int i = tid; i < V; i += FNT) {
        float x = lg[i] / t;
        uint32_t u = f2u(x);
        if (u >= uk && u > up) {
            float w = expf(x - M);
            if (use_mp && (w / Z2) < thr) continue;
            float sc = (w / Z3) / fmaxf(nz[i], 1e-10f);
            if (sc > bs) { bs = sc; bi = i; }
        }
    }
    s_red[tid] = bs;
    int* ibuf = reinterpret_cast<int*>(s_cand);
    ibuf[tid] = bi;
    __syncthreads();
    for (int o = FNT / 2; o > 0; o >>= 1) {
        if (tid < o) {
            float v2 = s_red[tid + o]; int i2 = ibuf[tid + o];
            if (v2 > s_red[tid] || (v2 == s_red[tid] && i2 < ibuf[tid])) {
                s_red[tid] = v2; ibuf[tid] = i2;
            }
        }
        __syncthreads();
    }
    if (tid == 0) out[row] = ibuf[0];
}

// ---------------- launch ----------------

extern "C" void kernel_launch(void* const* d_in, const int* in_sizes, int n_in,
                              void* d_out, int out_size, void* d_ws, size_t ws_size,
                              hipStream_t stream) {
    const float* logits = (const float*)d_in[0];
    const float* temps  = (const float*)d_in[1];
    const int*   topks  = (const int*)d_in[2];
    const float* topps  = (const float*)d_in[3];
    const float* minps  = (const float*)d_in[4];
    const float* noise  = (const float*)d_in[5];
    const int B = in_sizes[1];
    const int V = in_sizes[0] / B;
    int* out = (int*)d_out;

    const int sliceLen = (((V + SLICES - 1) / SLICES) + 1023) & ~1023;

    const size_t offCU  = 0;
    const size_t offCI  = offCU + (size_t)B * SLICES * SUBCAP * 4;
    const size_t offCnt = offCI + (size_t)B * SLICES * SUBCAP * 4;
    const size_t need   = offCnt + (size_t)B * SLICES * 4;

    if (ws_size >= need && (V & 3) == 0 && (size_t)SLICES * (size_t)sliceLen >= (size_t)V) {
        char* ws = (char*)d_ws;
        uint32_t* cand_u  = (uint32_t*)(ws + offCU);
        int*      cand_ix = (int*)(ws + offCI);
        uint32_t* candCnt = (uint32_t*)(ws + offCnt);

        dim3 gslice(SLICES, B);
        k1_collect<<<gslice, K1T, 0, stream>>>(logits, temps, cand_u, cand_ix, candCnt, V, sliceLen);
        k4_final<<<B, KT4, 0, stream>>>(topks, topps, minps, noise, candCnt, cand_u, cand_ix, out, V);
    } else {
        sampler_fallback_kernel<<<B, FNT, 0, stream>>>(logits, temps, topks, topps, minps, noise, out, V);
    }
}

// Round 6
// 66.467 us; speedup vs baseline: 5.7676x; 1.4434x over previous
//
#include <hip/hip_runtime.h>
#include <cstdint>
#include <cmath>

// ---------------- tunables ----------------
#define SLICES 16
#define SUBCAP 384
#define CAPT (SLICES * SUBCAP)   // 6144
#define KT4 1024                 // k4 block size (16 waves)
#define NJ (CAPT / KT4)          // 6 strided iterations in k4
#define K1T 256                  // k1 block size
#define THRC 1.9f                // k1 collect threshold = mu + THRC*sigma

// order-preserving float<->uint bijection
static __device__ __forceinline__ uint32_t f2u(float f) {
    uint32_t b = __float_as_uint(f);
    return (b & 0x80000000u) ? ~b : (b | 0x80000000u);
}
static __device__ __forceinline__ float u2f(uint32_t u) {
    uint32_t b = (u & 0x80000000u) ? (u ^ 0x80000000u) : ~u;
    return __uint_as_float(b);
}

static __device__ __forceinline__ uint32_t wave_incl_u(uint32_t v) {
    int lane = threadIdx.x & 63;
#pragma unroll
    for (int o = 1; o < 64; o <<= 1) {
        uint32_t t = __shfl_up(v, (unsigned)o);
        if (lane >= o) v += t;
    }
    return v;
}
static __device__ __forceinline__ float wave_incl_f(float v) {
    int lane = threadIdx.x & 63;
#pragma unroll
    for (int o = 1; o < 64; o <<= 1) {
        float t = __shfl_up(v, (unsigned)o);
        if (lane >= o) v += t;
    }
    return v;
}

// ---------------- two-stage (2-round) descents over a 1024-bin LDS hist ----------------
// Whole block participates (chunk sums by 16 waves); decision in wave 0.

// counts: first bin b (desc) with above < target <= above + h[b]; exact.
static __device__ void ts_desc_count(const uint32_t* __restrict__ h, uint32_t target,
                                     uint32_t* cs, int* out_bin, uint32_t* out_above) {
    const int tid = threadIdx.x, lane = tid & 63, wv = tid >> 6;
    uint32_t v = h[wv * 64 + lane];
#pragma unroll
    for (int o = 32; o > 0; o >>= 1) v += __shfl_xor(v, o);
    if (lane == 0) cs[wv] = v;
    __syncthreads();
    if (tid < 64) {
        uint32_t w = (lane < 16) ? cs[15 - lane] : 0u;
        uint32_t incl = wave_incl_u(w);
        uint32_t Sb = incl - w;                       // strictly above chunk (15-lane)
        bool cross = (lane < 16) && (Sb < target) && (Sb + w >= target);
        unsigned long long m = __ballot(cross);
        if (m == 0) {
            uint32_t tot = __shfl(incl, 15);
            if (lane == 0) { *out_bin = -1; *out_above = tot; }
        } else {
            int l = (int)__ffsll(m) - 1;
            int cl = 15 - l;
            uint32_t Scl = __shfl(Sb, l);
            uint32_t wb = h[cl * 64 + 63 - lane];
            uint32_t incb = wave_incl_u(wb);
            uint32_t Sbb = Scl + incb - wb;
            bool cr2 = (Sbb < target) && (Sbb + wb >= target);
            unsigned long long m2 = __ballot(cr2);    // guaranteed nonzero for counts
            int l2 = (int)__ffsll(m2) - 1;
            if (lane == l2) { *out_bin = cl * 64 + 63 - lane; *out_above = Sbb; }
        }
    }
    __syncthreads();
}

// weighted crossing vs absolute target with running base. Deterministic forced
// resolution if stage-A/stage-B float rounding disagree (ulp-boundary class).
static __device__ void ts_desc_wcross(const float* __restrict__ h, float Sbase, float target,
                                      float* cs, int* out_bin, float* out_S) {
    const int tid = threadIdx.x, lane = tid & 63, wv = tid >> 6;
    float v = h[wv * 64 + lane];
#pragma unroll
    for (int o = 32; o > 0; o >>= 1) v += __shfl_xor(v, o);
    if (lane == 0) cs[wv] = v;
    __syncthreads();
    if (tid < 64) {
        float w = (lane < 16) ? cs[15 - lane] : 0.f;
        float incl = wave_incl_f(w);
        float Sb = Sbase + incl - w;
        bool cross = (lane < 16) && (Sb < target) && (Sb + w >= target);
        unsigned long long m = __ballot(cross);
        if (m == 0) {
            float tot = __shfl(incl, 15);
            if (lane == 0) { *out_bin = -1; *out_S = Sbase + tot; }
        } else {
            int l = (int)__ffsll(m) - 1;
            int cl = 15 - l;
            float Scl = __shfl(Sb, l);
            float wb = h[cl * 64 + 63 - lane];
            float incb = wave_incl_f(wb);
            float Sbb = Scl + incb - wb;
            bool cr2 = (Sbb < target) && (Sbb + wb >= target);
            unsigned long long m2 = __ballot(cr2);
            if (m2 == 0) cr2 = (lane == 63);          // force at lowest bin of chunk
            m2 = __ballot(cr2);
            int l2 = (int)__ffsll(m2) - 1;
            if (lane == l2) { *out_bin = cl * 64 + 63 - lane; *out_S = Sbb; }
        }
    }
    __syncthreads();
}

// classic 16-round VALUE rule (final top-p level only; runs once per row):
// first nonempty bin (desc) with strict-above-suffix >= target.
static __device__ void d1024_wvalue(const float* __restrict__ h, float Sbase, float target,
                                    int* out_bin, float* out_S) {
    if (threadIdx.x < 64) {
        const int lane = threadIdx.x;
        float S = Sbase;
        for (int r0 = 1023; r0 >= 0; r0 -= 64) {
            int b = r0 - lane;
            float w = h[b];
            float incl = wave_incl_f(w);
            float Sb = S + (incl - w);
            bool cross = (w > 0.f) && (Sb >= target);
            unsigned long long m = __ballot(cross);
            if (m) {
                int l = (int)__ffsll(m) - 1;
                if (lane == l) { *out_bin = b; *out_S = Sb; }
                return;
            }
            S += __shfl(incl, 63);
        }
        if (lane == 0) { *out_bin = -1; *out_S = S; }
    }
}

// ---------- 1024-thread (16-wave) block reductions ----------
static __device__ __forceinline__ unsigned long long shflxor_u64(unsigned long long v, int o) {
    uint32_t lo = (uint32_t)v, hi = (uint32_t)(v >> 32);
    lo = __shfl_xor(lo, o); hi = __shfl_xor(hi, o);
    return ((unsigned long long)hi << 32) | (unsigned long long)lo;
}
static __device__ float blk16_sum(float v, float* rb) {
#pragma unroll
    for (int o = 32; o > 0; o >>= 1) v += __shfl_xor(v, o);
    const int wv = threadIdx.x >> 6;
    if ((threadIdx.x & 63) == 0) rb[wv] = v;
    __syncthreads();
    float r = (threadIdx.x < 16) ? rb[threadIdx.x] : 0.f;
    if (threadIdx.x < 64) {
#pragma unroll
        for (int o = 8; o > 0; o >>= 1) r += __shfl_xor(r, o);
        if (threadIdx.x == 0) rb[0] = r;
    }
    __syncthreads();
    r = rb[0];
    __syncthreads();
    return r;
}
static __device__ uint32_t blk16_max_u32(uint32_t v, uint32_t* rb) {
#pragma unroll
    for (int o = 32; o > 0; o >>= 1) { uint32_t x = __shfl_xor(v, o); if (x > v) v = x; }
    const int wv = threadIdx.x >> 6;
    if ((threadIdx.x & 63) == 0) rb[wv] = v;
    __syncthreads();
    uint32_t r = (threadIdx.x < 16) ? rb[threadIdx.x] : 0u;
    if (threadIdx.x < 64) {
#pragma unroll
        for (int o = 8; o > 0; o >>= 1) { uint32_t x = __shfl_xor(r, o); if (x > r) r = x; }
        if (threadIdx.x == 0) rb[0] = r;
    }
    __syncthreads();
    r = rb[0];
    __syncthreads();
    return r;
}
static __device__ uint32_t blk16_min_u32(uint32_t v, uint32_t* rb) {
#pragma unroll
    for (int o = 32; o > 0; o >>= 1) { uint32_t x = __shfl_xor(v, o); if (x < v) v = x; }
    const int wv = threadIdx.x >> 6;
    if ((threadIdx.x & 63) == 0) rb[wv] = v;
    __syncthreads();
    uint32_t r = (threadIdx.x < 16) ? rb[threadIdx.x] : 0xFFFFFFFFu;
    if (threadIdx.x < 64) {
#pragma unroll
        for (int o = 8; o > 0; o >>= 1) { uint32_t x = __shfl_xor(r, o); if (x < r) r = x; }
        if (threadIdx.x == 0) rb[0] = r;
    }
    __syncthreads();
    r = rb[0];
    __syncthreads();
    return r;
}
static __device__ unsigned long long blk16_max_u64(unsigned long long v, unsigned long long* rb) {
#pragma unroll
    for (int o = 32; o > 0; o >>= 1) { unsigned long long x = shflxor_u64(v, o); if (x > v) v = x; }
    const int wv = threadIdx.x >> 6;
    if ((threadIdx.x & 63) == 0) rb[wv] = v;
    __syncthreads();
    unsigned long long r = (threadIdx.x < 16) ? rb[threadIdx.x] : 0ull;
    if (threadIdx.x < 64) {
#pragma unroll
        for (int o = 8; o > 0; o >>= 1) { unsigned long long x = shflxor_u64(r, o); if (x > r) r = x; }
        if (threadIdx.x == 0) rb[0] = r;
    }
    __syncthreads();
    r = rb[0];
    __syncthreads();
    return r;
}

// ---------------- K1: stats-threshold collect (single HBM pass + L1/L2-hot re-read) ----------------

__global__ __launch_bounds__(K1T) void k1_collect(
    const float* __restrict__ logits, const float* __restrict__ temps,
    uint32_t* __restrict__ cand_u, int* __restrict__ cand_ix,
    uint32_t* __restrict__ candCnt, int V, int sliceLen)
{
    const int row = blockIdx.y, slice = blockIdx.x, tid = threadIdx.x;
    const int lane = tid & 63, wv = tid >> 6;
    __shared__ float redm[4], reds[4], redq[4];
    __shared__ float s_thr;
    __shared__ int wsum[4];
    __shared__ int s_base;

    const int base = slice * sliceLen;
    int len = V - base;
    if (len > sliceLen) len = sliceLen;
    if (len <= 0) { if (tid == 0) candCnt[row * SLICES + slice] = 0u; return; }

    const float* lg = logits + (size_t)row * (size_t)V;
    const float4* p4 = (const float4*)(lg + base);
    const int n4 = len >> 2;

    float mx = -INFINITY, sm = 0.f, sq = 0.f;
    for (int i = tid; i < n4; i += K1T) {
        float4 v = p4[i];
        mx = fmaxf(mx, fmaxf(fmaxf(v.x, v.y), fmaxf(v.z, v.w)));
        sm += (v.x + v.y) + (v.z + v.w);
        sq += (v.x * v.x + v.y * v.y) + (v.z * v.z + v.w * v.w);
    }
#pragma unroll
    for (int o = 32; o > 0; o >>= 1) {
        mx = fmaxf(mx, __shfl_xor(mx, o));
        sm += __shfl_xor(sm, o);
        sq += __shfl_xor(sq, o);
    }
    if (lane == 0) { redm[wv] = mx; reds[wv] = sm; redq[wv] = sq; }
    __syncthreads();
    if (tid == 0) {
        float m = redm[0], s = reds[0], q = redq[0];
        for (int w = 1; w < 4; w++) { m = fmaxf(m, redm[w]); s += reds[w]; q += redq[w]; }
        float inv = 1.f / (float)len;
        float mu = s * inv;
        float var = fmaxf(q * inv - mu * mu, 0.f);
        float thr = mu + THRC * sqrtf(var);
        if (thr > m) thr = m;
        s_thr = thr;
        s_base = 0;
    }
    __syncthreads();
    const float thr = s_thr;
    const float t = temps[row];
    uint32_t* cu = cand_u + ((size_t)row * SLICES + slice) * SUBCAP;
    int* cix = cand_ix + ((size_t)row * SLICES + slice) * SUBCAP;

    for (int c0 = 0; c0 < len; c0 += K1T * 4) {
        const int i0 = c0 + tid * 4;
        bool k0 = false, k1b = false, k2b = false, k3b = false;
        float4 v = make_float4(0.f, 0.f, 0.f, 0.f);
        if (i0 < len) {
            v = *(const float4*)(lg + base + i0);
            k0 = (v.x >= thr); k1b = (v.y >= thr); k2b = (v.z >= thr); k3b = (v.w >= thr);
        }
        int cnt = (int)k0 + (int)k1b + (int)k2b + (int)k3b;
        int inc = cnt;
#pragma unroll
        for (int o = 1; o < 64; o <<= 1) {
            int x = __shfl_up(inc, (unsigned)o);
            if (lane >= o) inc += x;
        }
        if (lane == 63) wsum[wv] = inc;
        __syncthreads();
        int woff = 0;
        for (int w = 0; w < wv; w++) woff += wsum[w];
        const int tot = wsum[0] + wsum[1] + wsum[2] + wsum[3];
        int p = s_base + woff + inc - cnt;
        if (k0)  { if (p < SUBCAP) { cu[p] = f2u(v.x / t); cix[p] = base + i0;     } p++; }
        if (k1b) { if (p < SUBCAP) { cu[p] = f2u(v.y / t); cix[p] = base + i0 + 1; } p++; }
        if (k2b) { if (p < SUBCAP) { cu[p] = f2u(v.z / t); cix[p] = base + i0 + 2; } p++; }
        if (k3b) { if (p < SUBCAP) { cu[p] = f2u(v.w / t); cix[p] = base + i0 + 3; } p++; }
        __syncthreads();
        if (tid == 0) s_base += tot;
        __syncthreads();
    }
    if (tid == 0) {
        int c = s_base; if (c > SUBCAP) c = SUBCAP;
        candCnt[row * SLICES + slice] = (uint32_t)c;
    }
}

// ---------------- K4: per-row finalize over <=6144 candidates, 1024 threads ----------------

__global__ __launch_bounds__(KT4, 1) void k4_final(
    const int* __restrict__ topks, const float* __restrict__ topps,
    const float* __restrict__ minps, const float* __restrict__ noise,
    const uint32_t* __restrict__ candCnt, const uint32_t* __restrict__ cand_u,
    const int* __restrict__ cand_ix, int* __restrict__ out, int V)
{
    const int row = blockIdx.x, tid = threadIdx.x;
    const int lane = tid & 63;
    __shared__ uint32_t s_u[CAPT];
    __shared__ int s_ix[CAPT];
    __shared__ float s_w[CAPT];
    __shared__ uint32_t s_hc[1024];          // count hist; aliased float for weighted
    __shared__ uint32_t s_cs[16];            // chunk sums (aliased float)
    __shared__ int s_off[SLICES + 1];
    __shared__ uint32_t rbu[16];
    __shared__ float rbf[16];
    __shared__ unsigned long long rbq[16];
    __shared__ int sh_bin; __shared__ uint32_t sh_above;
    __shared__ float sh_S; __shared__ float sh_W;
    float* s_hw = (float*)s_hc;
    float* csf = (float*)s_cs;

    const float pp = topps[row];
    const float mp = minps[row];
    int k = topks[row]; if (k < 1) k = 1; if (k > V) k = V;

    // s_off via wave-0 scan of candCnt
    if (tid < 64) {
        uint32_t c = 0;
        if (lane < SLICES) {
            c = candCnt[row * SLICES + lane];
            if (c > SUBCAP) c = SUBCAP;
        }
        uint32_t incl = wave_incl_u(c);
        if (lane < SLICES) s_off[lane] = (int)(incl - c);
        if (lane == SLICES - 1) s_off[SLICES] = (int)incl;
    }
    __syncthreads();
    const int n = s_off[SLICES];

    // load candidates (16 independent segments, all pipelined)
    uint32_t um = 0u, un = 0xFFFFFFFFu;
    for (int s = 0; s < SLICES; s++) {
        const int o0 = s_off[s], c = s_off[s + 1] - o0;
        const size_t gb = ((size_t)row * SLICES + s) * SUBCAP;
        if (tid < c) {
            uint32_t u = cand_u[gb + tid];
            s_u[o0 + tid] = u;
            s_ix[o0 + tid] = cand_ix[gb + tid];
            if (u > um) um = u;
            if (u < un) un = u;
        }
    }
    __syncthreads();
    const uint32_t umax = blk16_max_u32(um, rbu);
    const uint32_t base = blk16_min_u32(un, rbu);

    // prefetch noise into registers (waitcnt lands after the descents) + s_w fill
    float nzreg[NJ];
#pragma unroll
    for (int j = 0; j < NJ; j++) {
        int i = tid + j * KT4;
        nzreg[j] = 1.0f;
        if (i < n) {
            nzreg[j] = noise[(size_t)row * (size_t)V + s_ix[i]];
            s_w[i] = expf(u2f(s_u[i]));
        }
    }

    const uint32_t diff = umax ^ base;
    const int hb = (diff == 0u) ? 0 : (31 - __clz(diff));
    int sh0 = hb - 9; if (sh0 < 0) sh0 = 0;

    // ---- exact top-k threshold uk: prefix-skip count descent (2-round per level) ----
    uint32_t selHi = (sh0 + 10 >= 32) ? 0u : (base >> (sh0 + 10));
    int sh = sh0, shPrev = sh0 + 10;
    uint32_t tk = (uint32_t)k;
    for (int lvl = 0; ; lvl++) {
        s_hc[tid] = 0u;
        __syncthreads();
#pragma unroll
        for (int j = 0; j < NJ; j++) {
            int i = tid + j * KT4;
            if (i < n) {
                uint32_t u = s_u[i];
                if (lvl == 0 || (u >> shPrev) == selHi)
                    atomicAdd(&s_hc[(u >> sh) & 1023u], 1u);
            }
        }
        __syncthreads();
        ts_desc_count(s_hc, tk, s_cs, &sh_bin, &sh_above);
        int b = sh_bin;
        uint32_t ab = sh_above;
        if (b < 0) { b = 0; ab = 0u; }   // k > n pathological guard
        tk = (tk > ab) ? (tk - ab) : 1u;
        int step = shPrev - sh; if (step > 10) step = 10;
        selHi = (selHi << step) | ((uint32_t)b & ((1u << step) - 1u));
        if (sh == 0) break;
        shPrev = sh;
        sh = (sh >= 10) ? (sh - 10) : 0;
    }
    const uint32_t uk = selHi;
    const float maxw = expf(u2f(umax));

    // ---- top-p boundary value up (mask kept u <= up) ----
    uint32_t up = 0u;
    if (sh0 == 0) {
        // degenerate: whole range fits one 1024-bin level -> W by reduction + value rule
        float wl = 0.f;
#pragma unroll
        for (int j = 0; j < NJ; j++) {
            int i = tid + j * KT4;
            if (i < n) { uint32_t u = s_u[i]; if (u >= uk) wl += s_w[i]; }
        }
        const float W = blk16_sum(wl, rbf);
        const float pW = pp * W;
        if (!(pW > 0.f)) {
            up = umax - 1u;
        } else {
            s_hc[tid] = 0u;
            __syncthreads();
#pragma unroll
            for (int j = 0; j < NJ; j++) {
                int i = tid + j * KT4;
                if (i < n) {
                    uint32_t u = s_u[i];
                    if (u >= uk) atomicAdd(&s_hw[u & 1023u], s_w[i]);
                }
            }
            __syncthreads();
            d1024_wvalue(s_hw, 0.f, pW, &sh_bin, &sh_S);
            __syncthreads();
            const int b = sh_bin;
            const uint32_t pfxBase = (base >> 10) << 10;
            up = (b < 0) ? (pfxBase - 1u) : (pfxBase | (uint32_t)b);
        }
    } else {
        // level 0: weighted hist of all kept (u>=uk); W integrated from chunk scan
        s_hc[tid] = 0u;
        __syncthreads();
#pragma unroll
        for (int j = 0; j < NJ; j++) {
            int i = tid + j * KT4;
            if (i < n) {
                uint32_t u = s_u[i];
                if (u >= uk) atomicAdd(&s_hw[(u >> sh0) & 1023u], s_w[i]);
            }
        }
        __syncthreads();
        {
            float v = s_hw[(tid >> 6) * 64 + lane];
#pragma unroll
            for (int o = 32; o > 0; o >>= 1) v += __shfl_xor(v, o);
            if (lane == 0) csf[tid >> 6] = v;
        }
        __syncthreads();
        if (tid < 64) {
            float w = (lane < 16) ? csf[15 - lane] : 0.f;
            float incl = wave_incl_f(w);
            float Wt = __shfl(incl, 15);
            if (lane == 0) sh_W = Wt;
            float target = pp * Wt;
            if (!(target > 0.f)) {
                if (lane == 0) sh_bin = -2;
            } else {
                float Sb = incl - w;
                bool cross = (lane < 16) && (Sb < target) && (Sb + w >= target);
                unsigned long long m = __ballot(cross);
                if (m == 0) {
                    if (lane == 0) sh_bin = -1;
                } else {
                    int l = (int)__ffsll(m) - 1;
                    int cl = 15 - l;
                    float Scl = __shfl(Sb, l);
                    float wb = s_hw[cl * 64 + 63 - lane];
                    float incb = wave_incl_f(wb);
                    float Sbb = Scl + incb - wb;
                    bool cr2 = (Sbb < target) && (Sbb + wb >= target);
                    unsigned long long m2 = __ballot(cr2);
                    if (m2 == 0) cr2 = (lane == 63);
                    m2 = __ballot(cr2);
                    int l2 = (int)__ffsll(m2) - 1;
                    if (lane == l2) { sh_bin = cl * 64 + 63 - lane; sh_S = Sbb; }
                }
            }
        }
        __syncthreads();
        const int b0 = sh_bin;
        if (b0 == -2) {
            up = umax - 1u;                       // p == 0: keep only the max
        } else if (b0 == -1) {
            up = 0u;                              // suffix never reaches pW: mask nothing
        } else {
            const float pW = pp * sh_W;
            float Sb = sh_S;
            uint32_t selP = (((sh0 + 10 >= 32) ? 0u : (base >> (sh0 + 10))) << 10) | (uint32_t)b0;
            int shPv = sh0, shp = (sh0 >= 10) ? (sh0 - 10) : 0;
            for (;;) {
                s_hc[tid] = 0u;
                __syncthreads();
#pragma unroll
                for (int j = 0; j < NJ; j++) {
                    int i = tid + j * KT4;
                    if (i < n) {
                        uint32_t u = s_u[i];
                        if (u >= uk && (u >> shPv) == selP)
                            atomicAdd(&s_hw[(u >> shp) & 1023u], s_w[i]);
                    }
                }
                __syncthreads();
                if (shp == 0) {
                    d1024_wvalue(s_hw, Sb, pW, &sh_bin, &sh_S);
                    __syncthreads();
                } else {
                    ts_desc_wcross(s_hw, Sb, pW, csf, &sh_bin, &sh_S);
                }
                const int b = sh_bin;
                if (b < 0) { up = (selP << shPv) - 1u; break; }
                int step = shPv - shp; if (step > 10) step = 10;
                selP = (selP << step) | ((uint32_t)b & ((1u << step) - 1u));
                if (shp == 0) { up = selP; break; }
                Sb = sh_S;
                shPv = shp;
                shp = (shp >= 10) ? (shp - 10) : 0;
            }
        }
    }
    if (up >= umax) up = umax - 1u;               // never mask the max
    __syncthreads();

    // ---- min-p (Z cancels: prob < maxprob*mp <=> w < maxw*mp) + scale-free argmax ----
    const bool use_mp = (mp > 0.f);
    const float A = mp * maxw;

    unsigned long long best = 0ull;
#pragma unroll
    for (int j = 0; j < NJ; j++) {
        int i = tid + j * KT4;
        if (i < n) {
            uint32_t u = s_u[i];
            if (u >= uk && u > up) {
                float w = s_w[i];
                if (!(use_mp && w < A)) {
                    int idx = s_ix[i];
                    float sc = w / fmaxf(nzreg[j], 1e-10f);
                    unsigned long long pk = ((unsigned long long)__float_as_uint(sc) << 32)
                                          | (unsigned long long)(~(uint32_t)idx);
                    if (pk > best) best = pk;
                }
            }
        }
    }
    best = blk16_max_u64(best, rbq);
    if (tid == 0) out[row] = (int)(~(uint32_t)(best & 0xffffffffull));
}

// ---------------- fallback: monolithic single-kernel path (unused when ws fits) ----------------

#define FNT 1024
#define FNB1 16384
#define FL1SH 18
#define FCAP 8192

static __device__ void wave_desc_count_f(const uint32_t* h, int hi, int lo, uint32_t target,
                                         int* out_bin, uint32_t* out_above) {
    if (threadIdx.x < 64) {
        int lane = threadIdx.x;
        uint32_t S = 0;
        for (int r0 = hi; r0 >= lo; r0 -= 64) {
            int b = r0 - lane;
            uint32_t w = (b >= lo) ? h[b] : 0u;
            uint32_t incl = wave_incl_u(w);
            uint32_t Sb = S + incl - w;
            bool cross = (Sb < target) && (Sb + w >= target);
            unsigned long long m = __ballot(cross);
            if (m) {
                int l = (int)__ffsll(m) - 1;
                if (lane == l) { *out_bin = b; *out_above = Sb; }
                return;
            }
            S += __shfl(incl, 63);
        }
        if (lane == 0) { *out_bin = -1; *out_above = S; }
    }
}
static __device__ void wave_desc_wcross_f(const float* h, int hi, int lo, float base, float target,
                                          int* out_bin, float* out_S) {
    if (threadIdx.x < 64) {
        int lane = threadIdx.x;
        float S = base;
        for (int r0 = hi; r0 >= lo; r0 -= 64) {
            int b = r0 - lane;
            float w = (b >= lo) ? h[b] : 0.f;
            float incl = wave_incl_f(w);
            float Sb = S + (incl - w);
            bool cross = (Sb < target) && (Sb + w >= target);
            unsigned long long m = __ballot(cross);
            if (m) {
                int l = (int)__ffsll(m) - 1;
                if (lane == l) { *out_bin = b; *out_S = Sb; }
                return;
            }
            S += __shfl(incl, 63);
        }
        if (lane == 0) { *out_bin = -1; *out_S = S; }
    }
}
static __device__ void wave_desc_wvalue_f(const float* h, int hi, int lo, float base, float target,
                                          int* out_bin, float* out_S) {
    if (threadIdx.x < 64) {
        int lane = threadIdx.x;
        float S = base;
        for (int r0 = hi; r0 >= lo; r0 -= 64) {
            int b = r0 - lane;
            float w = (b >= lo) ? h[b] : 0.f;
            float incl = wave_incl_f(w);
            float Sb = S + (incl - w);
            bool cross = (w > 0.f) && (Sb >= target);
            unsigned long long m = __ballot(cross);
            if (m) {
                int l = (int)__ffsll(m) - 1;
                if (lane == l) { *out_bin = b; *out_S = Sb; }
                return;
            }
            S += __shfl(incl, 63);
        }
        if (lane == 0) { *out_bin = -1; *out_S = S; }
    }
}
static __device__ float fblk_max_f(float v, float* buf) {
    int tid = threadIdx.x;
    buf[tid] = v; __syncthreads();
    for (int o = FNT / 2; o > 0; o >>= 1) {
        if (tid < o) buf[tid] = fmaxf(buf[tid], buf[tid + o]);
        __syncthreads();
    }
    float r = buf[0]; __syncthreads();
    return r;
}
static __device__ float fblk_sum_f(float v, float* buf) {
    int tid = threadIdx.x;
    buf[tid] = v; __syncthreads();
    for (int o = FNT / 2; o > 0; o >>= 1) {
        if (tid < o) buf[tid] += buf[tid + o];
        __syncthreads();
    }
    float r = buf[0]; __syncthreads();
    return r;
}

__global__ __launch_bounds__(FNT, 1) void sampler_fallback_kernel(
    const float* __restrict__ logits, const float* __restrict__ temps,
    const int* __restrict__ topks, const float* __restrict__ topps,
    const float* __restrict__ minps, const float* __restrict__ noise,
    int* __restrict__ out, int V)
{
    __shared__ uint32_t s_hist[FNB1];
    __shared__ uint32_t s_cand[FCAP];
    __shared__ float    s_red[FNT];
    __shared__ uint32_t s_h2[512];
    __shared__ int      sh_bin;
    __shared__ uint32_t sh_above;
    __shared__ int      sh_nc;
    __shared__ int      sh_binw;
    __shared__ float    sh_S;

    const int row = blockIdx.x;
    const int tid = threadIdx.x;
    const int lane = tid & 63;
    const float t  = temps[row];
    const float pp = topps[row];
    const float mp = minps[row];
    int k = topks[row];
    if (k < 1) k = 1;
    if (k > V) k = V;
    const float* lg = logits + (size_t)row * (size_t)V;
    const float* nz = noise  + (size_t)row * (size_t)V;

    for (int i = tid; i < FNB1; i += FNT) s_hist[i] = 0u;
    __syncthreads();

    float lmax = -INFINITY;
    for (int i = tid; i < V; i += FNT) {
        float x = lg[i] / t;
        lmax = fmaxf(lmax, x);
        atomicAdd(&s_hist[f2u(x) >> FL1SH], 1u);
    }
    const float M = fblk_max_f(lmax, s_red);
    const uint32_t umax = f2u(M);
    const int bmax = (int)(umax >> FL1SH);

    wave_desc_count_f(s_hist, bmax, 0, (uint32_t)k, &sh_bin, &sh_above);
    __syncthreads();
    const int b1 = sh_bin;
    const uint32_t cntHi = sh_above;

    float* wh = reinterpret_cast<float*>(s_hist);
    for (int i = tid; i < FNB1; i += FNT) wh[i] = 0.f;
    if (tid == 0) sh_nc = 0;
    __syncthreads();
    for (int i = tid; i < V; i += FNT) {
        float x = lg[i] / t;
        uint32_t u = f2u(x);
        atomicAdd(&wh[u >> FL1SH], expf(x - M));
        bool want = ((int)(u >> FL1SH) == b1);
        unsigned long long mb = __ballot(want);
        if (want) {
            int leader = (int)__ffsll(mb) - 1;
            int off = (int)__popcll(mb & ((1ull << lane) - 1ull));
            int bse = 0;
            if (lane == leader) bse = atomicAdd(&sh_nc, (int)__popcll(mb));
            bse = __shfl(bse, leader);
            int p = bse + off;
            if (p < FCAP) s_cand[p] = u;
        }
    }
    __syncthreads();
    int nc = sh_nc; if (nc > FCAP) nc = FCAP;
    const uint32_t kk2 = (uint32_t)k - cntHi;

    for (int i = tid; i < 512; i += FNT) s_h2[i] = 0u;
    __syncthreads();
    for (int i = tid; i < nc; i += FNT) atomicAdd(&s_h2[(s_cand[i] >> 9) & 511u], 1u);
    __syncthreads();
    wave_desc_count_f(s_h2, 511, 0, kk2, &sh_bin, &sh_above);
    __syncthreads();
    const int c2 = sh_bin;
    const uint32_t kk3 = kk2 - sh_above;

    for (int i = tid; i < 512; i += FNT) s_h2[i] = 0u;
    __syncthreads();
    for (int i = tid; i < nc; i += FNT) {
        uint32_t u = s_cand[i];
        if ((int)((u >> 9) & 511u) == c2) atomicAdd(&s_h2[u & 511u], 1u);
    }
    __syncthreads();
    wave_desc_count_f(s_h2, 511, 0, kk3, &sh_bin, &sh_above);
    __syncthreads();
    const uint32_t uk = ((uint32_t)b1 << FL1SH) | ((uint32_t)c2 << 9) | (uint32_t)sh_bin;

    float wl = 0.f;
    for (int i = tid; i < nc; i += FNT) {
        uint32_t u = s_cand[i];
        if (u >= uk) wl += expf(u2f(u) - M);
    }
    const float Wb1 = fblk_sum_f(wl, s_red);
    if (tid == 0) wh[b1] = Wb1;
    __syncthreads();
    float sl = 0.f;
    for (int i = tid; i < FNB1; i += FNT)
        if (i >= b1 && i <= bmax) sl += wh[i];
    const float W = fblk_sum_f(sl, s_red);
    const float pW = pp * W;

    uint32_t up = 0u;
    float Z2 = W;
    if (pW <= 0.f) {
        up = umax - 1u;
        Z2 = 1.0f;
    } else {
        wave_desc_wcross_f(wh, bmax, b1, 0.f, pW, &sh_binw, &sh_S);
        __syncthreads();
        const int cs = sh_binw;
        if (cs >= 0) {
            const float S1 = sh_S;
            if (cs != b1) {
                if (tid == 0) sh_nc = 0;
                __syncthreads();
                for (int i = tid; i < V; i += FNT) {
                    float x = lg[i] / t;
                    uint32_t u = f2u(x);
                    bool want = (u >= uk) && ((int)(u >> FL1SH) == cs);
                    unsigned long long mb = __ballot(want);
                    if (want) {
                        int leader = (int)__ffsll(mb) - 1;
                        int off = (int)__popcll(mb & ((1ull << lane) - 1ull));
                        int bse = 0;
                        if (lane == leader) bse = atomicAdd(&sh_nc, (int)__popcll(mb));
                        bse = __shfl(bse, leader);
                        int p = bse + off;
                        if (p < FCAP) s_cand[p] = u;
                    }
                }
                __syncthreads();
                nc = sh_nc; if (nc > FCAP) nc = FCAP;
            }
            float* wh2 = reinterpret_cast<float*>(s_h2);
            for (int i = tid; i < 512; i += FNT) wh2[i] = 0.f;
            __syncthreads();
            for (int i = tid; i < nc; i += FNT) {
                uint32_t u = s_cand[i];
                if (u >= uk) atomicAdd(&wh2[(u >> 9) & 511u], expf(u2f(u) - M));
            }
            __syncthreads();
            wave_desc_wcross_f(wh2, 511, 0, S1, pW, &sh_binw, &sh_S);
            __syncthreads();
            const int c2p = sh_binw;
            if (c2p < 0) {
                uint32_t basev = (uint32_t)cs << FL1SH;
                up = basev ? basev - 1u : 0u;
                Z2 = sh_S;
            } else {
                const float S2 = sh_S;
                for (int i = tid; i < 512; i += FNT) wh2[i] = 0.f;
                __syncthreads();
                for (int i = tid; i < nc; i += FNT) {
                    uint32_t u = s_cand[i];
                    if (u >= uk && (int)((u >> 9) & 511u) == c2p)
                        atomicAdd(&wh2[u & 511u], expf(u2f(u) - M));
                }
                __syncthreads();
                wave_desc_wvalue_f(wh2, 511, 0, S2, pW, &sh_binw, &sh_S);
                __syncthreads();
                if (sh_binw < 0) {
                    uint32_t basev = ((uint32_t)cs << FL1SH) | ((uint32_t)c2p << 9);
                    up = basev ? basev - 1u : 0u;
                    Z2 = sh_S;
                } else {
                    up = ((uint32_t)cs << FL1SH) | ((uint32_t)c2p << 9) | (uint32_t)sh_binw;
                    Z2 = sh_S;
                }
            }
        }
        if (up >= umax) { up = umax - 1u; Z2 = 1.0f; }
    }
    __syncthreads();

    const bool use_mp = (mp > 0.f);
    const float thr = mp * (1.0f / Z2);

    float zl = 0.f;
    for (int i = tid; i < V; i += FNT) {
        float x = lg[i] / t;
        uint32_t u = f2u(x);
        if (u >= uk && u > up) {
            float w = expf(x - M);
            if (use_mp && (w / Z2) < thr) continue;
            zl += w;
        }
    }
    const float Z3 = fblk_sum_f(zl, s_red);

    float bs = -1.f; int bi = 0x7fffffff;
    for (int i = tid; i < V; i += FNT) {
        float x = lg[i] / t;
        uint32_t u = f2u(x);
        if (u >= uk && u > up) {
            float w = expf(x - M);
            if (use_mp && (w / Z2) < thr) continue;
            float sc = (w / Z3) / fmaxf(nz[i], 1e-10f);
            if (sc > bs) { bs = sc; bi = i; }
        }
    }
    s_red[tid] = bs;
    int* ibuf = reinterpret_cast<int*>(s_cand);
    ibuf[tid] = bi;
    __syncthreads();
    for (int o = FNT / 2; o > 0; o >>= 1) {
        if (tid < o) {
            float v2 = s_red[tid + o]; int i2 = ibuf[tid + o];
            if (v2 > s_red[tid] || (v2 == s_red[tid] && i2 < ibuf[tid])) {
                s_red[tid] = v2; ibuf[tid] = i2;
            }
        }
        __syncthreads();
    }
    if (tid == 0) out[row] = ibuf[0];
}

// ---------------- launch ----------------

extern "C" void kernel_launch(void* const* d_in, const int* in_sizes, int n_in,
                              void* d_out, int out_size, void* d_ws, size_t ws_size,
                              hipStream_t stream) {
    const float* logits = (const float*)d_in[0];
    const float* temps  = (const float*)d_in[1];
    const int*   topks  = (const int*)d_in[2];
    const float* topps  = (const float*)d_in[3];
    const float* minps  = (const float*)d_in[4];
    const float* noise  = (const float*)d_in[5];
    const int B = in_sizes[1];
    const int V = in_sizes[0] / B;
    int* out = (int*)d_out;

    const int sliceLen = (((V + SLICES - 1) / SLICES) + 1023) & ~1023;

    const size_t offCU  = 0;
    const size_t offCI  = offCU + (size_t)B * SLICES * SUBCAP * 4;
    const size_t offCnt = offCI + (size_t)B * SLICES * SUBCAP * 4;
    const size_t need   = offCnt + (size_t)B * SLICES * 4;

    if (ws_size >= need && (V & 3) == 0 && (size_t)SLICES * (size_t)sliceLen >= (size_t)V) {
        char* ws = (char*)d_ws;
        uint32_t* cand_u  = (uint32_t*)(ws + offCU);
        int*      cand_ix = (int*)(ws + offCI);
        uint32_t* candCnt = (uint32_t*)(ws + offCnt);

        dim3 gslice(SLICES, B);
        k1_collect<<<gslice, K1T, 0, stream>>>(logits, temps, cand_u, cand_ix, candCnt, V, sliceLen);
        k4_final<<<B, KT4, 0, stream>>>(topks, topps, minps, noise, candCnt, cand_u, cand_ix, out, V);
    } else {
        sampler_fallback_kernel<<<B, FNT, 0, stream>>>(logits, temps, topks, topps, minps, noise, out, V);
    }
}

// Round 7
// 52.759 us; speedup vs baseline: 7.2660x; 1.2598x over previous
//
#include <hip/hip_runtime.h>
#include <cstdint>
#include <cmath>

typedef unsigned long long ull;

// ---------------- tunables ----------------
#define SLICES 16
#define SUBCAP 384              // 64 lanes x 6 regs per wave
#define NR 6
#define KT4 1024                // k4 threads (16 waves)
#define K1T 512                 // k1 threads (8 waves)
#define SPRE 4096               // k1 stats prefix elements
#define THRC 1.9f
#define NB8 8192                // k4 hist bins
#define NCK 128                 // chunks of 64 bins

// order-preserving float<->uint bijection
static __device__ __forceinline__ uint32_t f2u(float f) {
    uint32_t b = __float_as_uint(f);
    return (b & 0x80000000u) ? ~b : (b | 0x80000000u);
}
static __device__ __forceinline__ float u2f(uint32_t u) {
    uint32_t b = (u & 0x80000000u) ? (u ^ 0x80000000u) : ~u;
    return __uint_as_float(b);
}

static __device__ __forceinline__ uint32_t wave_incl_u(uint32_t v) {
    int lane = threadIdx.x & 63;
#pragma unroll
    for (int o = 1; o < 64; o <<= 1) {
        uint32_t t = __shfl_up(v, (unsigned)o);
        if (lane >= o) v += t;
    }
    return v;
}
static __device__ __forceinline__ float wave_incl_f(float v) {
    int lane = threadIdx.x & 63;
#pragma unroll
    for (int o = 1; o < 64; o <<= 1) {
        float t = __shfl_up(v, (unsigned)o);
        if (lane >= o) v += t;
    }
    return v;
}

// ---------------- two-stage descents over 8192-bin LDS hist (128 chunks) ----------------
// All waves build chunk sums; wave 0 decides in <=3 scan rounds. Trailing barrier.

static __device__ void ts8k_count(const uint32_t* __restrict__ h, uint32_t target,
                                  uint32_t* cs, int* out_bin, uint32_t* out_above) {
    const int tid = threadIdx.x, lane = tid & 63, wv = tid >> 6;
#pragma unroll
    for (int m = 0; m < NCK / 16; m++) {
        int cc = wv * (NCK / 16) + m;
        uint32_t x = h[cc * 64 + lane];
#pragma unroll
        for (int o = 32; o > 0; o >>= 1) x += __shfl_xor(x, o);
        if (lane == 0) cs[cc] = x;
    }
    __syncthreads();
    if (tid < 64) {
        uint32_t S = 0; int foundc = -1; uint32_t Sc = 0;
        for (int r0 = NCK - 1; r0 >= 0; r0 -= 64) {
            int cc = r0 - lane;
            uint32_t wq = (cc >= 0) ? cs[cc] : 0u;
            uint32_t incl = wave_incl_u(wq);
            uint32_t Sb = S + incl - wq;
            bool cross = (Sb < target) && (Sb + wq >= target);
            ull m = __ballot(cross);
            if (m) { int l = (int)__ffsll(m) - 1; foundc = __shfl(cc, l); Sc = __shfl(Sb, l); break; }
            S += __shfl(incl, 63);
        }
        if (foundc < 0) {
            if (lane == 0) { *out_bin = -1; *out_above = S; }
        } else {
            uint32_t wb = h[foundc * 64 + 63 - lane];
            uint32_t incb = wave_incl_u(wb);
            uint32_t Sbb = Sc + incb - wb;
            bool cr = (Sbb < target) && (Sbb + wb >= target);
            ull m2 = __ballot(cr);                 // exact integers: nonzero
            int l2 = (int)__ffsll(m2) - 1;
            if (lane == l2) { *out_bin = foundc * 64 + 63 - lane; *out_above = Sbb; }
        }
    }
    __syncthreads();
}

static __device__ void ts8k_wcross(const float* __restrict__ h, float Sbase, float target,
                                   float* cs, int* out_bin, float* out_S) {
    const int tid = threadIdx.x, lane = tid & 63, wv = tid >> 6;
#pragma unroll
    for (int m = 0; m < NCK / 16; m++) {
        int cc = wv * (NCK / 16) + m;
        float x = h[cc * 64 + lane];
#pragma unroll
        for (int o = 32; o > 0; o >>= 1) x += __shfl_xor(x, o);
        if (lane == 0) cs[cc] = x;
    }
    __syncthreads();
    if (tid < 64) {
        float S = Sbase; int foundc = -1; float Sc = 0.f;
        for (int r0 = NCK - 1; r0 >= 0; r0 -= 64) {
            int cc = r0 - lane;
            float wq = (cc >= 0) ? cs[cc] : 0.f;
            float incl = wave_incl_f(wq);
            float Sb = S + incl - wq;
            bool cross = (Sb < target) && (Sb + wq >= target);
            ull m = __ballot(cross);
            if (m) { int l = (int)__ffsll(m) - 1; foundc = __shfl(cc, l); Sc = __shfl(Sb, l); break; }
            S += __shfl(incl, 63);
        }
        if (foundc < 0) {
            if (lane == 0) { *out_bin = -1; *out_S = S; }
        } else {
            float wb = h[foundc * 64 + 63 - lane];
            float incb = wave_incl_f(wb);
            float Sbb = Sc + incb - wb;
            bool cr = (Sbb < target) && (Sbb + wb >= target);
            ull m2 = __ballot(cr);
            if (m2 == 0) cr = (lane == 63);        // deterministic forced resolution
            m2 = __ballot(cr);
            int l2 = (int)__ffsll(m2) - 1;
            if (lane == l2) { *out_bin = foundc * 64 + 63 - lane; *out_S = Sbb; }
        }
    }
    __syncthreads();
}

// ---------- 16-wave block reductions ----------
static __device__ __forceinline__ ull shflxor_u64(ull v, int o) {
    uint32_t lo = (uint32_t)v, hi = (uint32_t)(v >> 32);
    lo = __shfl_xor(lo, o); hi = __shfl_xor(hi, o);
    return ((ull)hi << 32) | (ull)lo;
}
static __device__ uint2 blk16_max2(uint32_t a, uint32_t b, uint32_t* rb /*32*/) {
#pragma unroll
    for (int o = 32; o > 0; o >>= 1) {
        uint32_t x = __shfl_xor(a, o); if (x > a) a = x;
        uint32_t y = __shfl_xor(b, o); if (y > b) b = y;
    }
    const int wv = threadIdx.x >> 6;
    if ((threadIdx.x & 63) == 0) { rb[wv] = a; rb[16 + wv] = b; }
    __syncthreads();
    if (threadIdx.x < 64) {
        const int lane = threadIdx.x;
        uint32_t ra = (lane < 16) ? rb[lane] : 0u;
        uint32_t rbv = (lane < 16) ? rb[16 + lane] : 0u;
#pragma unroll
        for (int o = 8; o > 0; o >>= 1) {
            uint32_t x = __shfl_xor(ra, o); if (x > ra) ra = x;
            uint32_t y = __shfl_xor(rbv, o); if (y > rbv) rbv = y;
        }
        if (lane == 0) { rb[0] = ra; rb[16] = rbv; }
    }
    __syncthreads();
    uint2 res; res.x = rb[0]; res.y = rb[16];
    __syncthreads();
    return res;
}
static __device__ ull blk16_max_u64(ull v, ull* rb) {
#pragma unroll
    for (int o = 32; o > 0; o >>= 1) { ull x = shflxor_u64(v, o); if (x > v) v = x; }
    const int wv = threadIdx.x >> 6;
    if ((threadIdx.x & 63) == 0) rb[wv] = v;
    __syncthreads();
    ull r = (threadIdx.x < 16) ? rb[threadIdx.x] : 0ull;
    if (threadIdx.x < 64) {
#pragma unroll
        for (int o = 8; o > 0; o >>= 1) { ull x = shflxor_u64(r, o); if (x > r) r = x; }
        if (threadIdx.x == 0) rb[0] = r;
    }
    __syncthreads();
    r = rb[0];
    __syncthreads();
    return r;
}

// ---------------- K1: single-pass collect (prefix stats) + noise gather ----------------

__global__ __launch_bounds__(K1T) void k1_collect(
    const float* __restrict__ logits, const float* __restrict__ temps,
    const float* __restrict__ noise,
    uint32_t* __restrict__ cand_u, int* __restrict__ cand_ix, float* __restrict__ cand_nz,
    uint32_t* __restrict__ candCnt, int V, int sliceLen)
{
    const int row = blockIdx.y, slice = blockIdx.x, tid = threadIdx.x;
    const int lane = tid & 63, wv = tid >> 6;   // 8 waves
    __shared__ float redm[8], reds[8], redq[8];
    __shared__ float s_thr;
    __shared__ int wsum[8];
    __shared__ int s_base;
    __shared__ uint32_t s_cu[SUBCAP];
    __shared__ int s_cix[SUBCAP];

    const int base = slice * sliceLen;
    int len = V - base;
    if (len > sliceLen) len = sliceLen;
    if (len <= 0) { if (tid == 0) candCnt[row * SLICES + slice] = 0u; return; }

    const float* lg = logits + (size_t)row * (size_t)V;
    const float4* p4 = (const float4*)(lg + base);

    // prefix stats (min(SPRE,len) elements)
    const int pre = (len < SPRE) ? len : SPRE;
    const int npre4 = pre >> 2;
    float mx = -INFINITY, sm = 0.f, sq = 0.f;
    for (int i = tid; i < npre4; i += K1T) {
        float4 v = p4[i];
        mx = fmaxf(mx, fmaxf(fmaxf(v.x, v.y), fmaxf(v.z, v.w)));
        sm += (v.x + v.y) + (v.z + v.w);
        sq += (v.x * v.x + v.y * v.y) + (v.z * v.z + v.w * v.w);
    }
#pragma unroll
    for (int o = 32; o > 0; o >>= 1) {
        mx = fmaxf(mx, __shfl_xor(mx, o));
        sm += __shfl_xor(sm, o);
        sq += __shfl_xor(sq, o);
    }
    if (lane == 0) { redm[wv] = mx; reds[wv] = sm; redq[wv] = sq; }
    __syncthreads();
    if (tid == 0) {
        float m = redm[0], s = reds[0], q = redq[0];
        for (int w = 1; w < 8; w++) { m = fmaxf(m, redm[w]); s += reds[w]; q += redq[w]; }
        float inv = 1.f / (float)pre;
        float mu = s * inv;
        float var = fmaxf(q * inv - mu * mu, 0.f);
        float thr = mu + THRC * sqrtf(var);
        if (thr > m) thr = m;       // guarantee >=1 kept
        s_thr = thr;
        s_base = 0;
    }
    __syncthreads();
    const float thr = s_thr;
    const float t = temps[row];

    // single collect pass (deterministic compaction into LDS)
    for (int c0 = 0; c0 < len; c0 += K1T * 4) {
        const int i0 = c0 + tid * 4;
        bool b0 = false, b1 = false, b2 = false, b3 = false;
        float4 v = make_float4(0.f, 0.f, 0.f, 0.f);
        if (i0 < len) {                 // len % 4 == 0 -> all four valid
            v = *(const float4*)(lg + base + i0);
            b0 = (v.x >= thr); b1 = (v.y >= thr); b2 = (v.z >= thr); b3 = (v.w >= thr);
        }
        int cnt = (int)b0 + (int)b1 + (int)b2 + (int)b3;
        int inc = cnt;
#pragma unroll
        for (int o = 1; o < 64; o <<= 1) {
            int x = __shfl_up(inc, (unsigned)o);
            if (lane >= o) inc += x;
        }
        if (lane == 63) wsum[wv] = inc;
        __syncthreads();
        int woff = 0;
        for (int q = 0; q < wv; q++) woff += wsum[q];
        int tot = 0;
        for (int q = 0; q < 8; q++) tot += wsum[q];
        int p = s_base + woff + inc - cnt;
        if (b0) { if (p < SUBCAP) { s_cu[p] = f2u(v.x / t); s_cix[p] = base + i0;     } p++; }
        if (b1) { if (p < SUBCAP) { s_cu[p] = f2u(v.y / t); s_cix[p] = base + i0 + 1; } p++; }
        if (b2) { if (p < SUBCAP) { s_cu[p] = f2u(v.z / t); s_cix[p] = base + i0 + 2; } p++; }
        if (b3) { if (p < SUBCAP) { s_cu[p] = f2u(v.w / t); s_cix[p] = base + i0 + 3; } p++; }
        __syncthreads();
        if (tid == 0) s_base += tot;
        __syncthreads();
    }

    // write-out + noise gather (one phase; cnt <= 384 < 512 threads)
    int cnt = s_base; if (cnt > SUBCAP) cnt = SUBCAP;
    const size_t gb = ((size_t)row * SLICES + slice) * SUBCAP;
    if (tid < cnt) {
        uint32_t uu = s_cu[tid];
        int gi = s_cix[tid];
        cand_u[gb + tid] = uu;
        cand_ix[gb + tid] = gi;
        cand_nz[gb + tid] = noise[(size_t)row * (size_t)V + gi];
    }
    if (tid == 0) candCnt[row * SLICES + slice] = (uint32_t)cnt;
}

// ---------------- K4: register-resident per-row finalize ----------------

__global__ __launch_bounds__(KT4, 1) void k4_final(
    const int* __restrict__ topks, const float* __restrict__ topps,
    const float* __restrict__ minps, const uint32_t* __restrict__ candCnt,
    const uint32_t* __restrict__ cand_u, const int* __restrict__ cand_ix,
    const float* __restrict__ cand_nz, int* __restrict__ out, int V)
{
    const int row = blockIdx.x, tid = threadIdx.x;
    const int lane = tid & 63, wv = tid >> 6;
    __shared__ uint32_t s_h[NB8];            // 32 KB; aliased float for weighted
    __shared__ uint32_t s_cs[NCK];           // chunk sums (aliased float)
    __shared__ uint32_t rb2[32];
    __shared__ ull rbq[16];
    __shared__ int sh_bin; __shared__ uint32_t sh_above;
    __shared__ float sh_S; __shared__ float sh_T;
    float* fh = (float*)s_h;
    float* csf = (float*)s_cs;

    const float pp = topps[row];
    const float mp = minps[row];
    int k = topks[row]; if (k < 1) k = 1; if (k > V) k = V;

    // wave wv owns slice wv: 384 slots = lane + 64*j
    int c = (int)candCnt[row * SLICES + wv]; if (c > SUBCAP) c = SUBCAP;
    const size_t gb = ((size_t)row * SLICES + wv) * SUBCAP;

    uint32_t u[NR]; float w[NR]; float nzv[NR]; int ix[NR];
#pragma unroll
    for (int j = 0; j < NR; j++) {
        const int idx = lane + 64 * j;
        u[j] = 0u; nzv[j] = 1.f; ix[j] = 0;
        if (idx < c) {
            u[j] = cand_u[gb + idx];
            ix[j] = cand_ix[gb + idx];
            nzv[j] = cand_nz[gb + idx];
        }
    }
    uint32_t um = 0u, unm = 0u;   // max u, max ~u over live (u=0 is dead sentinel)
#pragma unroll
    for (int j = 0; j < NR; j++) {
        w[j] = (u[j] != 0u) ? expf(u2f(u[j])) : 0.f;
        if (u[j] > um) um = u[j];
        uint32_t nu = (u[j] != 0u) ? ~u[j] : 0u;
        if (nu > unm) unm = nu;
    }
    uint2 mm = blk16_max2(um, unm, rb2);
    const uint32_t umax = mm.x;
    const uint32_t ubase = ~mm.y;
    const uint32_t R = umax - ubase;
    const int sh0 = (R < (uint32_t)NB8) ? 0 : ((31 - __clz(R)) - 12);

    uint32_t r[NR];
#pragma unroll
    for (int j = 0; j < NR; j++) r[j] = u[j] - ubase;   // dead: r > R always

    // ---- exact top-k rel-threshold ukr: 13-bit-step count descent ----
    uint32_t tk = (uint32_t)k, sel = 0u;
    int sh = sh0, shPrev = sh0 + 13;
    bool first = true;
    for (;;) {
        for (int i = tid; i < NB8; i += KT4) s_h[i] = 0u;
        __syncthreads();
#pragma unroll
        for (int j = 0; j < NR; j++) {
            uint32_t rj = r[j];
            if (rj <= R && (first || (rj >> shPrev) == sel))
                atomicAdd(&s_h[(rj >> sh) & (NB8 - 1)], 1u);
        }
        __syncthreads();
        ts8k_count(s_h, tk, s_cs, &sh_bin, &sh_above);
        int b = sh_bin; uint32_t ab = sh_above;
        if (b < 0) { b = 0; ab = 0u; }           // k > n guard
        tk = (tk > ab) ? (tk - ab) : 1u;
        const int step = first ? 13 : (shPrev - sh);
        sel = (sel << step) | (uint32_t)b;
        if (sh == 0) break;
        shPrev = sh;
        sh = (sh >= 13) ? sh - 13 : 0;
        first = false;
    }
    const uint32_t ukr = sel;

    // ---- top-p: weighted descent -> rel crossing value vcr (mask = kept r < vcr) ----
    uint32_t vcr = 0u;
    {
        for (int i = tid; i < NB8; i += KT4) fh[i] = 0.f;
        __syncthreads();
#pragma unroll
        for (int j = 0; j < NR; j++) {
            uint32_t rj = r[j];
            if (rj <= R && rj >= ukr)
                atomicAdd(&fh[(rj >> sh0) & (NB8 - 1)], w[j]);
        }
        __syncthreads();
        // chunk sums + W + level-0 decision (wave 0)
#pragma unroll
        for (int m = 0; m < NCK / 16; m++) {
            int cc = wv * (NCK / 16) + m;
            float x = fh[cc * 64 + lane];
#pragma unroll
            for (int o = 32; o > 0; o >>= 1) x += __shfl_xor(x, o);
            if (lane == 0) csf[cc] = x;
        }
        __syncthreads();
        if (tid < 64) {
            float t0 = csf[lane] + csf[64 + lane];
#pragma unroll
            for (int o = 32; o > 0; o >>= 1) t0 += __shfl_xor(t0, o);
            const float Wt = t0;
            const float target = pp * Wt;
            if (lane == 0) sh_T = target;
            if (!(target > 0.f)) {
                if (lane == 0) sh_bin = -2;        // p == 0
            } else {
                float S = 0.f; int foundc = -1; float Sc = 0.f;
                for (int r0 = NCK - 1; r0 >= 0; r0 -= 64) {
                    int cc = r0 - lane;
                    float wq = (cc >= 0) ? csf[cc] : 0.f;
                    float incl = wave_incl_f(wq);
                    float Sb = S + incl - wq;
                    bool cross = (Sb < target) && (Sb + wq >= target);
                    ull m = __ballot(cross);
                    if (m) { int l = (int)__ffsll(m) - 1; foundc = __shfl(cc, l); Sc = __shfl(Sb, l); break; }
                    S += __shfl(incl, 63);
                }
                if (foundc < 0) {
                    if (lane == 0) sh_bin = -1;    // suffix never reaches target
                } else {
                    float wb = fh[foundc * 64 + 63 - lane];
                    float incb = wave_incl_f(wb);
                    float Sbb = Sc + incb - wb;
                    bool cr = (Sbb < target) && (Sbb + wb >= target);
                    ull m2 = __ballot(cr);
                    if (m2 == 0) cr = (lane == 63);
                    m2 = __ballot(cr);
                    int l2 = (int)__ffsll(m2) - 1;
                    if (lane == l2) { sh_bin = foundc * 64 + 63 - lane; sh_S = Sbb; }
                }
            }
        }
        __syncthreads();
        const int b0 = sh_bin;
        const float pW = sh_T;
        if (b0 == -2) {
            vcr = R;                               // keep only max
        } else if (b0 == -1) {
            vcr = 0u;                              // mask nothing
        } else if (sh0 == 0) {
            vcr = (uint32_t)b0;                    // exact value
        } else {
            uint32_t selp = (uint32_t)b0;
            int shPv = sh0;
            int shp = (sh0 >= 13) ? sh0 - 13 : 0;
            float Sb = sh_S;
            for (;;) {
                for (int i = tid; i < NB8; i += KT4) fh[i] = 0.f;
                __syncthreads();
#pragma unroll
                for (int j = 0; j < NR; j++) {
                    uint32_t rj = r[j];
                    if (rj <= R && rj >= ukr && (rj >> shPv) == selp)
                        atomicAdd(&fh[(rj >> shp) & (NB8 - 1)], w[j]);
                }
                __syncthreads();
                ts8k_wcross(fh, Sb, pW, csf, &sh_bin, &sh_S);
                int b = sh_bin;
                if (b < 0) { vcr = selp << shPv; break; }     // float-edge: keep whole class
                selp = (selp << (shPv - shp)) | (uint32_t)b;
                if (shp == 0) { vcr = selp; break; }
                Sb = sh_S;
                shPv = shp;
                shp = (shp >= 13) ? shp - 13 : 0;
            }
        }
        if (vcr > R) vcr = R;                      // never mask the max
    }

    // ---- min-p (Z cancels) + scale-free noise argmax over registers ----
    const float maxw = expf(u2f(umax));
    const bool use_mp = (mp > 0.f);
    const float A = mp * maxw;

    ull best = 0ull;
#pragma unroll
    for (int j = 0; j < NR; j++) {
        uint32_t rj = r[j];
        if (rj <= R && rj >= ukr && rj >= vcr) {
            float wj = w[j];
            if (!(use_mp && wj < A)) {
                float sc = wj / fmaxf(nzv[j], 1e-10f);
                ull pk = ((ull)__float_as_uint(sc) << 32) | (ull)(~(uint32_t)ix[j]);
                if (pk > best) best = pk;
            }
        }
    }
    best = blk16_max_u64(best, rbq);
    if (tid == 0) out[row] = (int)(~(uint32_t)(best & 0xffffffffull));
}

// ---------------- fallback: monolithic single-kernel path (ws too small / odd V) ----------------

#define FNT 1024
#define FNB1 16384
#define FL1SH 18
#define FCAP 8192

static __device__ void wave_desc_count_f(const uint32_t* h, int hi, int lo, uint32_t target,
                                         int* out_bin, uint32_t* out_above) {
    if (threadIdx.x < 64) {
        int lane = threadIdx.x;
        uint32_t S = 0;
        for (int r0 = hi; r0 >= lo; r0 -= 64) {
            int b = r0 - lane;
            uint32_t w = (b >= lo) ? h[b] : 0u;
            uint32_t incl = wave_incl_u(w);
            uint32_t Sb = S + incl - w;
            bool cross = (Sb < target) && (Sb + w >= target);
            ull m = __ballot(cross);
            if (m) {
                int l = (int)__ffsll(m) - 1;
                if (lane == l) { *out_bin = b; *out_above = Sb; }
                return;
            }
            S += __shfl(incl, 63);
        }
        if (lane == 0) { *out_bin = -1; *out_above = S; }
    }
}
static __device__ void wave_desc_wcross_f(const float* h, int hi, int lo, float base, float target,
                                          int* out_bin, float* out_S) {
    if (threadIdx.x < 64) {
        int lane = threadIdx.x;
        float S = base;
        for (int r0 = hi; r0 >= lo; r0 -= 64) {
            int b = r0 - lane;
            float w = (b >= lo) ? h[b] : 0.f;
            float incl = wave_incl_f(w);
            float Sb = S + (incl - w);
            bool cross = (Sb < target) && (Sb + w >= target);
            ull m = __ballot(cross);
            if (m) {
                int l = (int)__ffsll(m) - 1;
                if (lane == l) { *out_bin = b; *out_S = Sb; }
                return;
            }
            S += __shfl(incl, 63);
        }
        if (lane == 0) { *out_bin = -1; *out_S = S; }
    }
}
static __device__ void wave_desc_wvalue_f(const float* h, int hi, int lo, float base, float target,
                                          int* out_bin, float* out_S) {
    if (threadIdx.x < 64) {
        int lane = threadIdx.x;
        float S = base;
        for (int r0 = hi; r0 >= lo; r0 -= 64) {
            int b = r0 - lane;
            float w = (b >= lo) ? h[b] : 0.f;
            float incl = wave_incl_f(w);
            float Sb = S + (incl - w);
            bool cross = (w > 0.f) && (Sb >= target);
            ull m = __ballot(cross);
            if (m) {
                int l = (int)__ffsll(m) - 1;
                if (lane == l) { *out_bin = b; *out_S = Sb; }
                return;
            }
            S += __shfl(incl, 63);
        }
        if (lane == 0) { *out_bin = -1; *out_S = S; }
    }
}
static __device__ float fblk_max_f(float v, float* buf) {
    int tid = threadIdx.x;
    buf[tid] = v; __syncthreads();
    for (int o = FNT / 2; o > 0; o >>= 1) {
        if (tid < o) buf[tid] = fmaxf(buf[tid], buf[tid + o]);
        __syncthreads();
    }
    float r = buf[0]; __syncthreads();
    return r;
}
static __device__ float fblk_sum_f(float v, float* buf) {
    int tid = threadIdx.x;
    buf[tid] = v; __syncthreads();
    for (int o = FNT / 2; o > 0; o >>= 1) {
        if (tid < o) buf[tid] += buf[tid + o];
        __syncthreads();
    }
    float r = buf[0]; __syncthreads();
    return r;
}

__global__ __launch_bounds__(FNT, 1) void sampler_fallback_kernel(
    const float* __restrict__ logits, const float* __restrict__ temps,
    const int* __restrict__ topks, const float* __restrict__ topps,
    const float* __restrict__ minps, const float* __restrict__ noise,
    int* __restrict__ out, int V)
{
    __shared__ uint32_t s_hist[FNB1];
    __shared__ uint32_t s_cand[FCAP];
    __shared__ float    s_red[FNT];
    __shared__ uint32_t s_h2[512];
    __shared__ int      sh_bin;
    __shared__ uint32_t sh_above;
    __shared__ int      sh_nc;
    __shared__ int      sh_binw;
    __shared__ float    sh_S;

    const int row = blockIdx.x;
    const int tid = threadIdx.x;
    const int lane = tid & 63;
    const float t  = temps[row];
    const float pp = topps[row];
    const float mp = minps[row];
    int k = topks[row];
    if (k < 1) k = 1;
    if (k > V) k = V;
    const float* lg = logits + (size_t)row * (size_t)V;
    const float* nz = noise  + (size_t)row * (size_t)V;

    for (int i = tid; i < FNB1; i += FNT) s_hist[i] = 0u;
    __syncthreads();

    float lmax = -INFINITY;
    for (int i = tid; i < V; i += FNT) {
        float x = lg[i] / t;
        lmax = fmaxf(lmax, x);
        atomicAdd(&s_hist[f2u(x) >> FL1SH], 1u);
    }
    const float M = fblk_max_f(lmax, s_red);
    const uint32_t umax = f2u(M);
    const int bmax = (int)(umax >> FL1SH);

    wave_desc_count_f(s_hist, bmax, 0, (uint32_t)k, &sh_bin, &sh_above);
    __syncthreads();
    const int b1 = sh_bin;
    const uint32_t cntHi = sh_above;

    float* wh = reinterpret_cast<float*>(s_hist);
    for (int i = tid; i < FNB1; i += FNT) wh[i] = 0.f;
    if (tid == 0) sh_nc = 0;
    __syncthreads();
    for (int i = tid; i < V; i += FNT) {
        float x = lg[i] / t;
        uint32_t u = f2u(x);
        atomicAdd(&wh[u >> FL1SH], expf(x - M));
        bool want = ((int)(u >> FL1SH) == b1);
        ull mb = __ballot(want);
        if (want) {
            int leader = (int)__ffsll(mb) - 1;
            int off = (int)__popcll(mb & ((1ull << lane) - 1ull));
            int bse = 0;
            if (lane == leader) bse = atomicAdd(&sh_nc, (int)__popcll(mb));
            bse = __shfl(bse, leader);
            int p = bse + off;
            if (p < FCAP) s_cand[p] = u;
        }
    }
    __syncthreads();
    int nc = sh_nc; if (nc > FCAP) nc = FCAP;
    const uint32_t kk2 = (uint32_t)k - cntHi;

    for (int i = tid; i < 512; i += FNT) s_h2[i] = 0u;
    __syncthreads();
    for (int i = tid; i < nc; i += FNT) atomicAdd(&s_h2[(s_cand[i] >> 9) & 511u], 1u);
    __syncthreads();
    wave_desc_count_f(s_h2, 511, 0, kk2, &sh_bin, &sh_above);
    __syncthreads();
    const int c2 = sh_bin;
    const uint32_t kk3 = kk2 - sh_above;

    for (int i = tid; i < 512; i += FNT) s_h2[i] = 0u;
    __syncthreads();
    for (int i = tid; i < nc; i += FNT) {
        uint32_t u = s_cand[i];
        if ((int)((u >> 9) & 511u) == c2) atomicAdd(&s_h2[u & 511u], 1u);
    }
    __syncthreads();
    wave_desc_count_f(s_h2, 511, 0, kk3, &sh_bin, &sh_above);
    __syncthreads();
    const uint32_t uk = ((uint32_t)b1 << FL1SH) | ((uint32_t)c2 << 9) | (uint32_t)sh_bin;

    float wl = 0.f;
    for (int i = tid; i < nc; i += FNT) {
        uint32_t u = s_cand[i];
        if (u >= uk) wl += expf(u2f(u) - M);
    }
    const float Wb1 = fblk_sum_f(wl, s_red);
    if (tid == 0) wh[b1] = Wb1;
    __syncthreads();
    float sl = 0.f;
    for (int i = tid; i < FNB1; i += FNT)
        if (i >= b1 && i <= bmax) sl += wh[i];
    const float W = fblk_sum_f(sl, s_red);
    const float pW = pp * W;

    uint32_t up = 0u;
    float Z2 = W;
    if (pW <= 0.f) {
        up = umax - 1u;
        Z2 = 1.0f;
    } else {
        wave_desc_wcross_f(wh, bmax, b1, 0.f, pW, &sh_binw, &sh_S);
        __syncthreads();
        const int cs = sh_binw;
        if (cs >= 0) {
            const float S1 = sh_S;
            if (cs != b1) {
                if (tid == 0) sh_nc = 0;
                __syncthreads();
                for (int i = tid; i < V; i += FNT) {
                    float x = lg[i] / t;
                    uint32_t u = f2u(x);
                    bool want = (u >= uk) && ((int)(u >> FL1SH) == cs);
                    ull mb = __ballot(want);
                    if (want) {
                        int leader = (int)__ffsll(mb) - 1;
                        int off = (int)__popcll(mb & ((1ull << lane) - 1ull));
                        int bse = 0;
                        if (lane == leader) bse = atomicAdd(&sh_nc, (int)__popcll(mb));
                        bse = __shfl(bse, leader);
                        int p = bse + off;
                        if (p < FCAP) s_cand[p] = u;
                    }
                }
                __syncthreads();
                nc = sh_nc; if (nc > FCAP) nc = FCAP;
            }
            float* wh2 = reinterpret_cast<float*>(s_h2);
            for (int i = tid; i < 512; i += FNT) wh2[i] = 0.f;
            __syncthreads();
            for (int i = tid; i < nc; i += FNT) {
                uint32_t u = s_cand[i];
                if (u >= uk) atomicAdd(&wh2[(u >> 9) & 511u], expf(u2f(u) - M));
            }
            __syncthreads();
            wave_desc_wcross_f(wh2, 511, 0, S1, pW, &sh_binw, &sh_S);
            __syncthreads();
            const int c2p = sh_binw;
            if (c2p < 0) {
                uint32_t basev = (uint32_t)cs << FL1SH;
                up = basev ? basev - 1u : 0u;
                Z2 = sh_S;
            } else {
                const float S2 = sh_S;
                for (int i = tid; i < 512; i += FNT) wh2[i] = 0.f;
                __syncthreads();
                for (int i = tid; i < nc; i += FNT) {
                    uint32_t u = s_cand[i];
                    if (u >= uk && (int)((u >> 9) & 511u) == c2p)
                        atomicAdd(&wh2[u & 511u], expf(u2f(u) - M));
                }
                __syncthreads();
                wave_desc_wvalue_f(wh2, 511, 0, S2, pW, &sh_binw, &sh_S);
                __syncthreads();
                if (sh_binw < 0) {
                    uint32_t basev = ((uint32_t)cs << FL1SH) | ((uint32_t)c2p << 9);
                    up = basev ? basev - 1u : 0u;
                    Z2 = sh_S;
                } else {
                    up = ((uint32_t)cs << FL1SH) | ((uint32_t)c2p << 9) | (uint32_t)sh_binw;
                    Z2 = sh_S;
                }
            }
        }
        if (up >= umax) { up = umax - 1u; Z2 = 1.0f; }
    }
    __syncthreads();

    const bool use_mp = (mp > 0.f);
    const float thr = mp * (1.0f / Z2);

    float zl = 0.f;
    for (int i = tid; i < V; i += FNT) {
        float x = lg[i] / t;
        uint32_t u = f2u(x);
        if (u >= uk && u > up) {
            float w = expf(x - M);
            if (use_mp && (w / Z2) < thr) continue;
            zl += w;
        }
    }
    const float Z3 = fblk_sum_f(zl, s_red);

    float bs = -1.f; int bi = 0x7fffffff;
    for (int i = tid; i < V; i += FNT) {
        float x = lg[i] / t;
        uint32_t u = f2u(x);
        if (u >= uk && u > up) {
            float w = expf(x - M);
            if (use_mp && (w / Z2) < thr) continue;
            float sc = (w / Z3) / fmaxf(nz[i], 1e-10f);
            if (sc > bs) { bs = sc; bi = i; }
        }
    }
    s_red[tid] = bs;
    int* ibuf = reinterpret_cast<int*>(s_cand);
    ibuf[tid] = bi;
    __syncthreads();
    for (int o = FNT / 2; o > 0; o >>= 1) {
        if (tid < o) {
            float v2 = s_red[tid + o]; int i2 = ibuf[tid + o];
            if (v2 > s_red[tid] || (v2 == s_red[tid] && i2 < ibuf[tid])) {
                s_red[tid] = v2; ibuf[tid] = i2;
            }
        }
        __syncthreads();
    }
    if (tid == 0) out[row] = ibuf[0];
}

// ---------------- launch ----------------

extern "C" void kernel_launch(void* const* d_in, const int* in_sizes, int n_in,
                              void* d_out, int out_size, void* d_ws, size_t ws_size,
                              hipStream_t stream) {
    const float* logits = (const float*)d_in[0];
    const float* temps  = (const float*)d_in[1];
    const int*   topks  = (const int*)d_in[2];
    const float* topps  = (const float*)d_in[3];
    const float* minps  = (const float*)d_in[4];
    const float* noise  = (const float*)d_in[5];
    const int B = in_sizes[1];
    const int V = in_sizes[0] / B;
    int* out = (int*)d_out;

    const int sliceLen = (((V + SLICES - 1) / SLICES) + 1023) & ~1023;

    const size_t nslot  = (size_t)B * SLICES * SUBCAP;
    const size_t offCU  = 0;
    const size_t offCI  = offCU + nslot * 4;
    const size_t offNZ  = offCI + nslot * 4;
    const size_t offCnt = offNZ + nslot * 4;
    const size_t need   = offCnt + (size_t)B * SLICES * 4;

    if (ws_size >= need && (V & 3) == 0 && (size_t)SLICES * (size_t)sliceLen >= (size_t)V) {
        char* ws = (char*)d_ws;
        uint32_t* cand_u  = (uint32_t*)(ws + offCU);
        int*      cand_ix = (int*)(ws + offCI);
        float*    cand_nz = (float*)(ws + offNZ);
        uint32_t* candCnt = (uint32_t*)(ws + offCnt);

        dim3 gslice(SLICES, B);
        k1_collect<<<gslice, K1T, 0, stream>>>(logits, temps, noise, cand_u, cand_ix,
                                               cand_nz, candCnt, V, sliceLen);
        k4_final<<<B, KT4, 0, stream>>>(topks, topps, minps, candCnt, cand_u, cand_ix,
                                        cand_nz, out, V);
    } else {
        sampler_fallback_kernel<<<B, FNT, 0, stream>>>(logits, temps, topks, topps, minps, noise, out, V);
    }
}